// Round 16
// baseline (655.126 us; speedup 1.0000x reference)
//
#include <hip/hip_runtime.h>
#include <hip/hip_bf16.h>

#define BB 16
#define LL 2048
#define DD 512
#define HH 1024
#define NL 4
#define MM (BB*LL)   // 32768

typedef __attribute__((ext_vector_type(8))) short bh8;
typedef __attribute__((ext_vector_type(4))) float f4;
typedef __attribute__((ext_vector_type(4))) unsigned short us4;

typedef __attribute__((address_space(3))) unsigned int lds_u32;
typedef __attribute__((address_space(1))) const unsigned int glob_u32;

__device__ __forceinline__ void gld_lds16(const void* g, void* l) {
    __builtin_amdgcn_global_load_lds((glob_u32*)g, (lds_u32*)l, 16, 0, 0);
}

__device__ __forceinline__ unsigned short f2bf(float f) {
    unsigned int u = __float_as_uint(f);
    unsigned int r = (u + 0x7FFFu + ((u >> 16) & 1u)) >> 16;
    return (unsigned short)r;
}
__device__ __forceinline__ float bf2f(unsigned short u) {
    return __uint_as_float(((unsigned int)u) << 16);
}

// fast GELU (tanh form, abs err ~1e-4)
__device__ __forceinline__ float gelu_f(float v) {
    float y = 0.7978845608028654f * v * fmaf(0.044715f, v * v, 1.0f);
    float e = __expf(2.0f * y);
    float th = 1.0f - 2.0f * __builtin_amdgcn_rcpf(e + 1.0f);
    return 0.5f * v * (1.0f + th);
}

// ---------------- FREQS_CIS table [L, D]
__global__ __launch_bounds__(256) void freqs_kernel(float* __restrict__ fr) {
    int idx = blockIdx.x * 256 + threadIdx.x;
    int l = idx >> 8;
    int j = idx & 255;
    float f = exp2f(-(float)j * 0.051905126482615036f);  // log2(10000)/256
    float a = (float)l * f;
    fr[(size_t)l * DD + j]       = cosf(a);
    fr[(size_t)l * DD + 256 + j] = sinf(a);
}

// ---------------- weight transpose+convert: [NL][R][C] f32 -> [NL][C][R] bf16
__global__ __launch_bounds__(256) void wtrans_kernel(const float* __restrict__ w,
                                                     unsigned short* __restrict__ wt,
                                                     int R, int C) {
    __shared__ float ls[64][65];
    int layer = blockIdx.z;
    int tr = blockIdx.y;
    int tc = blockIdx.x;
    const float* src = w + (size_t)layer * R * C + (size_t)(tr * 64) * C + tc * 64;
    int t = threadIdx.x;
    #pragma unroll
    for (int s = 0; s < 4; s++) {
        int r = (t >> 4) + 16 * s, c = (t & 15) * 4;
        f4 v = *(const f4*)(src + (size_t)r * C + c);
        ls[r][c] = v.x; ls[r][c + 1] = v.y; ls[r][c + 2] = v.z; ls[r][c + 3] = v.w;
    }
    __syncthreads();
    unsigned short* dst = wt + (size_t)layer * R * C + (size_t)(tc * 64) * R + tr * 64;
    #pragma unroll
    for (int s = 0; s < 2; s++) {
        int idx = t + 256 * s;
        int c = idx >> 3;
        int r8 = (idx & 7) * 8;
        bh8 o;
        #pragma unroll
        for (int e = 0; e < 8; e++) o[e] = (short)f2bf(ls[r8 + e][c]);
        *(bh8*)(dst + (size_t)c * R + r8) = o;
    }
}

// ---------------- bias2[n] = pw2_b[n] + sum_k grn_b[k] * W2[k][n]
__global__ __launch_bounds__(256) void bias2_kernel(const float* __restrict__ pw2_b,
                                                    const float* __restrict__ grn_b,
                                                    const unsigned short* __restrict__ w2t,
                                                    float* __restrict__ bias2) {
    int layer = blockIdx.x;
    for (int n = threadIdx.x; n < DD; n += 256) {
        const unsigned short* wp = w2t + (size_t)layer * DD * HH + (size_t)n * HH;
        const float* gbp = grn_b + (size_t)layer * HH;
        float s = 0.f;
        for (int k8 = 0; k8 < HH; k8 += 8) {
            bh8 wv = *(const bh8*)(wp + k8);
            #pragma unroll
            for (int e = 0; e < 8; e++) s = fmaf(gbp[k8 + e], bf2f((unsigned short)wv[e]), s);
        }
        bias2[(size_t)layer * DD + n] = pw2_b[(size_t)layer * DD + n] + s;
    }
}

// ---------------- embedding + freqs + mask -> bf16 x
__global__ __launch_bounds__(64) void embed_kernel(const int* __restrict__ text,
                                                   const float* __restrict__ table,
                                                   const float* __restrict__ fr,
                                                   unsigned short* __restrict__ x) {
    int bid = blockIdx.x;            // b*L + l
    int t = threadIdx.x;             // 64 lanes, 8 ch each
    int l = bid & (LL - 1);
    int d0 = t * 8;
    int tok = text[bid] + 1;
    bh8 o;
    if (tok != 0) {
        const float* e = table + (size_t)tok * DD + d0;
        const float* f = fr + (size_t)l * DD + d0;
        #pragma unroll
        for (int k = 0; k < 8; k++) o[k] = (short)f2bf(e[k] + f[k]);
    } else {
        #pragma unroll
        for (int k = 0; k < 8; k++) o[k] = 0;
    }
    *(bh8*)(x + (size_t)bid * DD + d0) = o;
}

// ---------------- depthwise conv7 + bias + LayerNorm -> bf16 (x input is bf16)
#define CCH 16
__global__ __launch_bounds__(256) void conv_ln_kernel(const unsigned short* __restrict__ x,
                                                      const float* __restrict__ dw_w,
                                                      const float* __restrict__ dw_b,
                                                      const float* __restrict__ ln_g,
                                                      const float* __restrict__ ln_b,
                                                      unsigned short* __restrict__ xln) {
    const int t = threadIdx.x;
    const int lane = t & 63, wv = t >> 6;
    const int chunk = blockIdx.x * 4 + wv;
    const int row0 = chunk * CCH;
    const int l0 = row0 & (LL - 1);
    const int d0 = lane * 8;
    const unsigned short* xb = x + ((size_t)(row0 >> 11) * LL) * DD + d0;

    float w[7][8], cb[8], g[8], be[8];
    #pragma unroll
    for (int e = 0; e < 8; e++) {
        #pragma unroll
        for (int k = 0; k < 7; k++) w[k][e] = dw_w[(d0 + e) * 7 + k];
        cb[e] = dw_b[d0 + e];
        g[e]  = ln_g[d0 + e];
        be[e] = ln_b[d0 + e];
    }

    float ring[8][8];
    #pragma unroll
    for (int ii = 0; ii < 8; ii++) {
        int i = ii - 3;
        int s = i & 7;
        int l = l0 + i;
        bool ok = (unsigned)l < LL;
        if (ok) {
            bh8 v = *(const bh8*)(xb + (size_t)l * DD);
            #pragma unroll
            for (int e = 0; e < 8; e++) ring[s][e] = bf2f((unsigned short)v[e]);
        } else {
            #pragma unroll
            for (int e = 0; e < 8; e++) ring[s][e] = 0.f;
        }
    }

    #pragma unroll
    for (int r = 0; r < CCH; r++) {
        float acc[8];
        #pragma unroll
        for (int e = 0; e < 8; e++) acc[e] = cb[e];
        #pragma unroll
        for (int k = 0; k < 7; k++) {
            int s = (r + k - 3) & 7;
            #pragma unroll
            for (int e = 0; e < 8; e++) acc[e] = fmaf(w[k][e], ring[s][e], acc[e]);
        }
        if (r + 5 <= CCH + 2) {
            int s = (r + 5) & 7;
            int l = l0 + r + 5;
            bool ok = (unsigned)l < LL;
            if (ok) {
                bh8 v = *(const bh8*)(xb + (size_t)l * DD);
                #pragma unroll
                for (int e = 0; e < 8; e++) ring[s][e] = bf2f((unsigned short)v[e]);
            } else {
                #pragma unroll
                for (int e = 0; e < 8; e++) ring[s][e] = 0.f;
            }
        }
        float s1 = 0.f, s2 = 0.f;
        #pragma unroll
        for (int e = 0; e < 8; e++) { s1 += acc[e]; s2 = fmaf(acc[e], acc[e], s2); }
        #pragma unroll
        for (int off = 1; off <= 32; off <<= 1) {
            s1 += __shfl_xor(s1, off, 64);
            s2 += __shfl_xor(s2, off, 64);
        }
        float mu = s1 * (1.0f / DD);
        float var = s2 * (1.0f / DD) - mu * mu;
        float rstd = rsqrtf(var + 1e-6f);
        bh8 o;
        #pragma unroll
        for (int e = 0; e < 8; e++) o[e] = (short)f2bf((acc[e] - mu) * rstd * g[e] + be[e]);
        *(bh8*)(xln + (size_t)(row0 + r) * DD + d0) = o;
    }
}

// ---------------- bf16 MFMA GEMM: 256x256 tile, 8 waves (2Mx4N), BK=32, dbuf = 64KB LDS
// -> 2 blocks/CU; cross-block overlap hides the per-tile vmcnt(0) drains.
// XOR swizzle for 4-chunk rows: read kq = ((lane>>4) ^ (ln&3))*8; stage source col
// ((tid&3) ^ ((tid>>2)&3))*8 (involution, both-sides). R9's provable drain-0 ledger.
// MODE 0 (GEMM1): h = bf16(gelu(C+bias)); writes 64-row-block partials of sum(h^2) to aux
// MODE 1 (GEMM2): B = per-batch pre-scaled W2 (batch = m0>>11); epilogue stages C+bias as
//   f32 in LDS (4 passes of 64x256 = 64KB), coalesced us4 RMW on bf16 x.
template<int KDIM, int NDIM, int MODE>
__global__ __launch_bounds__(512) void gemm_bf16_kernel(const unsigned short* __restrict__ A,
                                                        const unsigned short* __restrict__ Bt,
                                                        const float* __restrict__ bias,
                                                        unsigned short* __restrict__ hout,
                                                        unsigned short* __restrict__ xio,
                                                        const int* __restrict__ text,
                                                        float* __restrict__ aux) {
    __shared__ unsigned short lsbuf[32768];    // 64KB: A dbuf (0..16383), B dbuf (16384..32767)
    const int tid = threadIdx.x;
    constexpr int NX = NDIM / 256;
    constexpr int NWG = NX * (MM / 256);
    constexpr int NT = KDIM / 32;
    const int id = blockIdx.y * NX + blockIdx.x;
    const int sw = (id & 7) * (NWG / 8) + (id >> 3);     // XCD-chunked (NWG%8==0)
    const int m0 = (sw / NX) * 256;
    const int n0 = (sw % NX) * 256;

    const int lane = tid & 63, wid = tid >> 6;
    const int wm = wid >> 2, wn = wid & 3;               // wave tile: 128 rows x 64 cols
    const int ln = lane & 15;
    const int kq = (((lane >> 4) ^ (ln & 3)) << 3);      // swizzled k offset (shorts)
    const int arow = (wm * 128 + ln) * 32;               // + i*512
    const int brow = (wn * 64 + ln) * 32;                // + j*512

    const int srow = tid >> 2;                           // 0..127
    const int scol = (((tid & 3) ^ ((tid >> 2) & 3)) << 3); // inverse-swizzled global col
    const int sdst = tid * 8;                            // LDS shorts (rows 0..127); +4096 hi
    const unsigned short* Asrc = A + ((size_t)m0 + srow) * KDIM + scol;
    const unsigned short* Bsrc;
    if constexpr (MODE == 0) Bsrc = Bt + ((size_t)n0 + srow) * KDIM + scol;
    else                     Bsrc = Bt + ((size_t)(m0 >> 11) * NDIM + n0 + srow) * KDIM + scol;

    f4 acc[8][4];
    #pragma unroll
    for (int i = 0; i < 8; i++)
        #pragma unroll
        for (int j = 0; j < 4; j++) acc[i][j] = (f4){0.f, 0.f, 0.f, 0.f};

#define LSA(bb) (lsbuf + (bb) * 8192)
#define LSB(bb) (lsbuf + 16384 + (bb) * 8192)
#define STG_ALL(bb, ko) do {                                                               \
    gld_lds16(Asrc + (ko), LSA(bb) + sdst);                                                \
    gld_lds16(Asrc + (size_t)128 * KDIM + (ko), LSA(bb) + 4096 + sdst);                    \
    gld_lds16(Bsrc + (ko), LSB(bb) + sdst);                                                \
    gld_lds16(Bsrc + (size_t)128 * KDIM + (ko), LSB(bb) + 4096 + sdst); } while (0)
#define BOUNDARY do { asm volatile("s_waitcnt vmcnt(0)" ::: "memory");                     \
    __builtin_amdgcn_s_barrier(); __builtin_amdgcn_sched_barrier(0); } while (0)

    STG_ALL(0, 0);
    BOUNDARY;

    for (int kt = 0; kt < NT; kt++) {
        const int cur = kt & 1;
        const bool more = (kt + 1 < NT);
        if (more) { STG_ALL(cur ^ 1, (kt + 1) * 32); }
        __builtin_amdgcn_sched_barrier(0);       // keep stage issues at top
        bh8 aF[8], bF[4];
        #pragma unroll
        for (int i = 0; i < 8; i++) aF[i] = *(bh8*)(LSA(cur) + arow + i * 512 + kq);
        #pragma unroll
        for (int j = 0; j < 4; j++) bF[j] = *(bh8*)(LSB(cur) + brow + j * 512 + kq);
        __builtin_amdgcn_s_setprio(1);
        #pragma unroll
        for (int i = 0; i < 8; i++)
            #pragma unroll
            for (int j = 0; j < 4; j++)
                acc[i][j] = __builtin_amdgcn_mfma_f32_16x16x32_bf16(aF[i], bF[j], acc[i][j], 0, 0, 0);
        __builtin_amdgcn_s_setprio(0);
        if (more) { BOUNDARY; }
    }
#undef STG_ALL
#undef BOUNDARY
#undef LSA
#undef LSB

    const int rowOff = (lane >> 4) * 4;
    const int colOff = ln;
    if constexpr (MODE == 0) {
        float sj0[4] = {0.f, 0.f, 0.f, 0.f};
        float sj1[4] = {0.f, 0.f, 0.f, 0.f};
        #pragma unroll
        for (int i = 0; i < 8; i++) {
            #pragma unroll
            for (int j = 0; j < 4; j++) {
                int n = n0 + wn * 64 + j * 16 + colOff;
                float bn = bias[n];
                #pragma unroll
                for (int r = 0; r < 4; r++) {
                    int m = m0 + wm * 128 + i * 16 + rowOff + r;
                    float v = gelu_f(acc[i][j][r] + bn);
                    hout[(size_t)m * NDIM + n] = f2bf(v);
                    if (i < 4) sj0[j] = fmaf(v, v, sj0[j]);
                    else       sj1[j] = fmaf(v, v, sj1[j]);
                }
            }
        }
        #pragma unroll
        for (int j = 0; j < 4; j++) {
            sj0[j] += __shfl_xor(sj0[j], 16, 64);
            sj0[j] += __shfl_xor(sj0[j], 32, 64);
            sj1[j] += __shfl_xor(sj1[j], 16, 64);
            sj1[j] += __shfl_xor(sj1[j], 32, 64);
        }
        if (lane < 16) {
            int rb = (m0 + wm * 128) >> 6;       // 64-row blocks
            #pragma unroll
            for (int j = 0; j < 4; j++) {
                aux[(size_t)rb * HH + n0 + wn * 64 + j * 16 + lane] = sj0[j];
                aux[(size_t)(rb + 1) * HH + n0 + wn * 64 + j * 16 + lane] = sj1[j];
            }
        }
    } else {
        // staged coalesced RMW epilogue: 4 passes of 64 rows x 256 cols f32 (64KB LDS)
        __syncthreads();                          // all waves done reading last K-tile
        float* cf = (float*)lsbuf;                // 64 x 256 f32 = 64KB
        #pragma unroll
        for (int p = 0; p < 4; p++) {
            const int half = p >> 1, qtr = p & 1;
            if (wm == half) {
                #pragma unroll
                for (int i = 0; i < 4; i++) {
                    int ii = qtr * 4 + i;
                    #pragma unroll
                    for (int j = 0; j < 4; j++) {
                        int lc = wn * 64 + j * 16 + colOff;
                        float bn = bias[n0 + lc];
                        #pragma unroll
                        for (int r = 0; r < 4; r++) {
                            int lr = ii * 16 + rowOff + r - qtr * 64;
                            cf[lr * 256 + lc] = acc[ii][j][r] + bn;
                        }
                    }
                }
            }
            __syncthreads();
            #pragma unroll
            for (int k = 0; k < 8; k++) {
                int ci = tid + 512 * k;           // 4096 chunks of 4 cols
                int row = ci >> 6, ch = ci & 63;
                int m = m0 + half * 128 + qtr * 64 + row;
                size_t gb = (size_t)m * NDIM + n0 + ch * 4;
                bool msk = (text[m] == -1);
                us4 xo = *(const us4*)(xio + gb);
                f4 c = *(const f4*)&cf[row * 256 + ch * 4];
                us4 onew;
                onew.x = msk ? 0 : f2bf(c.x + bf2f(xo.x));
                onew.y = msk ? 0 : f2bf(c.y + bf2f(xo.y));
                onew.z = msk ? 0 : f2bf(c.z + bf2f(xo.z));
                onew.w = msk ? 0 : f2bf(c.w + bf2f(xo.w));
                *(us4*)(xio + gb) = onew;
            }
            __syncthreads();
        }
    }
}

// ---------------- GRN stats: scale[b][ch] = 1 + gg[ch] * Nx[b][ch]
__global__ __launch_bounds__(256) void grn_stats_kernel(const float* __restrict__ gxp,
                                                        const float* __restrict__ gg,
                                                        float* __restrict__ scale) {
    int b = blockIdx.x, t = threadIdx.x;
    float g[4];
    float s = 0.f;
    #pragma unroll
    for (int e = 0; e < 4; e++) {
        int ch = t + e * 256;
        float acc = 0.f;
        #pragma unroll
        for (int rb = 0; rb < 32; rb++) acc += gxp[(size_t)(b * 32 + rb) * HH + ch];
        g[e] = sqrtf(acc);
        s += g[e];
    }
    #pragma unroll
    for (int off = 32; off > 0; off >>= 1) s += __shfl_down(s, off);
    __shared__ float rs[4];
    if ((t & 63) == 0) rs[t >> 6] = s;
    __syncthreads();
    float tot = rs[0] + rs[1] + rs[2] + rs[3];
    float mean = tot * (1.0f / HH);
    float inv = 1.0f / (mean + 1e-6f);
    #pragma unroll
    for (int e = 0; e < 4; e++) {
        int ch = t + e * 256;
        scale[(size_t)b * HH + ch] = fmaf(gg[ch], g[e] * inv, 1.0f);
    }
}

// ---------------- per-batch scaled W2: w2s[b][n][k] = bf16(scale[b][k] * w2t[n][k])
__global__ __launch_bounds__(256) void w2scale_kernel(const unsigned short* __restrict__ w2t,
                                                      const float* __restrict__ scale,
                                                      unsigned short* __restrict__ w2s) {
    int b = blockIdx.y;
    size_t idx = ((size_t)blockIdx.x * 256 + threadIdx.x) * 8;   // over DD*HH
    int k = (int)(idx & (HH - 1));
    bh8 w = *(const bh8*)(w2t + idx);
    f4 s0 = *(const f4*)(scale + (size_t)b * HH + k);
    f4 s1 = *(const f4*)(scale + (size_t)b * HH + k + 4);
    float sv[8] = {s0.x,s0.y,s0.z,s0.w,s1.x,s1.y,s1.z,s1.w};
    bh8 o;
    #pragma unroll
    for (int e = 0; e < 8; e++) o[e] = (short)f2bf(bf2f((unsigned short)w[e]) * sv[e]);
    *(bh8*)(w2s + (size_t)b * DD * HH + idx) = o;
}

// ---------------- upsample scan (wave-ballot scan: 2 barriers/chunk)
__global__ __launch_bounds__(256) void upscan_kernel(const int* __restrict__ text,
                                                     const int* __restrict__ audio,
                                                     int* __restrict__ pos,
                                                     int* __restrict__ lens) {
    int b = blockIdx.x, t = threadIdx.x;
    int lane = t & 63, wv = t >> 6;
    __shared__ int wt[4], wa[4];
    int voff = 0, aoff = 0;
    for (int c = 0; c < LL / 256; c++) {
        int l = c * 256 + t;
        int am = audio[(size_t)b * LL + l];
        int tv = text[(size_t)b * LL + l];
        int valid = (am != 0 && tv != -1) ? 1 : 0;
        unsigned long long mv = __ballot(valid);
        unsigned long long ma = __ballot(am != 0);
        if (lane == 0) { wt[wv] = __popcll(mv); wa[wv] = __popcll(ma); }
        __syncthreads();
        int pre = 0;
        #pragma unroll
        for (int w = 0; w < 4; w++) if (w < wv) pre += wt[w];
        int incl = pre + (int)__popcll(mv << (63 - lane));   // bits 0..lane
        if (valid) pos[(size_t)b * LL + voff + incl - 1] = l;
        int bt = wt[0] + wt[1] + wt[2] + wt[3];
        int ba = wa[0] + wa[1] + wa[2] + wa[3];
        __syncthreads();
        voff += bt;
        aoff += ba;
    }
    if (t == 0) { lens[b * 2] = aoff; lens[b * 2 + 1] = voff; }
    for (int i = voff + t; i < LL; i += 256) pos[(size_t)b * LL + i] = LL - 1;
}

// ---------------- upsample gather (x bf16 -> out f32; 128 threads x 4 elems)
__global__ __launch_bounds__(128) void upgather_kernel(const unsigned short* __restrict__ x,
                                                       const int* __restrict__ pos,
                                                       const int* __restrict__ lens,
                                                       float* __restrict__ out) {
    int bid = blockIdx.x;
    int b = bid >> 11;
    int p = bid & (LL - 1);
    int t = threadIdx.x;
    int alen = lens[b * 2], vlen = lens[b * 2 + 1];
    f4 v = {0.f, 0.f, 0.f, 0.f};
    if (p < alen && vlen > 0) {
        int vl = vlen < 1 ? 1 : vlen;
        int base = alen / vl, rem = alen % vl;
        int cut = (vl - rem) * base;
        int j;
        if (p < cut) j = p / (base < 1 ? 1 : base);
        else j = (vl - rem) + (p - cut) / (base + 1);
        j = j < 0 ? 0 : (j > LL - 1 ? LL - 1 : j);
        int s = pos[(size_t)b * LL + j];
        s = s < 0 ? 0 : (s > LL - 1 ? LL - 1 : s);
        us4 u = *(const us4*)(x + ((size_t)b * LL + s) * DD + t * 4);
        v.x = bf2f(u.x); v.y = bf2f(u.y); v.z = bf2f(u.z); v.w = bf2f(u.w);
    }
    *(f4*)(out + (size_t)bid * DD + t * 4) = v;
}

// ---------------- workspace layout (bytes)
#define OFF_FREQS  ((size_t)0)
#define OFF_X      (OFF_FREQS + (size_t)LL * DD * 4)          // 4 MB (freqs f32)
#define OFF_XLN    (OFF_X + (size_t)MM * DD * 2)              // +32 MB (x bf16)
#define OFF_H      (OFF_XLN + (size_t)MM * DD * 2)            // +32 MB
#define OFF_W1T    (OFF_H + (size_t)MM * HH * 2)              // +64 MB
#define OFF_W2T    (OFF_W1T + (size_t)NL * HH * DD * 2)       // +4 MB
#define OFF_GXP    (OFF_W2T + (size_t)NL * DD * HH * 2)       // +4 MB
#define OFF_NX     (OFF_GXP + (size_t)512 * HH * 4)           // +2 MB
#define OFF_B2     (OFF_NX + (size_t)BB * HH * 4)             // +64 KB
#define OFF_POS    (OFF_B2 + (size_t)NL * DD * 4)             // +8 KB
#define OFF_LENS   (OFF_POS + (size_t)BB * LL * 4)            // +128 KB
// w2s (16 MB) overlays xln's region (xln dead between GEMM1(layer) and conv_ln(layer+1))
#define OFF_W2S    OFF_XLN

extern "C" void kernel_launch(void* const* d_in, const int* in_sizes, int n_in,
                              void* d_out, int out_size, void* d_ws, size_t ws_size,
                              hipStream_t stream) {
    const int*   text  = (const int*)d_in[0];
    const int*   audio = (const int*)d_in[1];
    const float* table = (const float*)d_in[3];
    const float* dw_w  = (const float*)d_in[4];
    const float* dw_b  = (const float*)d_in[5];
    const float* ln_g  = (const float*)d_in[6];
    const float* ln_b  = (const float*)d_in[7];
    const float* pw1_w = (const float*)d_in[8];
    const float* pw1_b = (const float*)d_in[9];
    const float* grn_g = (const float*)d_in[10];
    const float* grn_b = (const float*)d_in[11];
    const float* pw2_w = (const float*)d_in[12];
    const float* pw2_b = (const float*)d_in[13];
    float* out = (float*)d_out;

    char* ws = (char*)d_ws;
    float*          freqs = (float*)(ws + OFF_FREQS);
    unsigned short* x     = (unsigned short*)(ws + OFF_X);
    unsigned short* xln   = (unsigned short*)(ws + OFF_XLN);
    unsigned short* h     = (unsigned short*)(ws + OFF_H);
    unsigned short* w1t   = (unsigned short*)(ws + OFF_W1T);
    unsigned short* w2t   = (unsigned short*)(ws + OFF_W2T);
    unsigned short* w2s   = (unsigned short*)(ws + OFF_W2S);
    float*          gxp   = (float*)(ws + OFF_GXP);
    float*          nx    = (float*)(ws + OFF_NX);
    float*          bias2 = (float*)(ws + OFF_B2);
    int*            pos   = (int*)(ws + OFF_POS);
    int*            lens  = (int*)(ws + OFF_LENS);

    freqs_kernel<<<LL, 256, 0, stream>>>(freqs);
    wtrans_kernel<<<dim3(HH / 64, DD / 64, NL), 256, 0, stream>>>(pw1_w, w1t, DD, HH);
    wtrans_kernel<<<dim3(DD / 64, HH / 64, NL), 256, 0, stream>>>(pw2_w, w2t, HH, DD);
    bias2_kernel<<<NL, 256, 0, stream>>>(pw2_b, grn_b, w2t, bias2);
    embed_kernel<<<MM, 64, 0, stream>>>(text, table, freqs, x);

    for (int layer = 0; layer < NL; layer++) {
        conv_ln_kernel<<<MM / (4 * CCH), 256, 0, stream>>>(x,
            dw_w + (size_t)layer * DD * 7, dw_b + (size_t)layer * DD,
            ln_g + (size_t)layer * DD, ln_b + (size_t)layer * DD, xln);

        gemm_bf16_kernel<DD, HH, 0><<<dim3(HH / 256, MM / 256), 512, 0, stream>>>(
            xln, w1t + (size_t)layer * HH * DD, pw1_b + (size_t)layer * HH,
            h, nullptr, nullptr, gxp);

        grn_stats_kernel<<<BB, 256, 0, stream>>>(gxp, grn_g + (size_t)layer * HH, nx);

        w2scale_kernel<<<dim3(DD * HH / (256 * 8), BB), 256, 0, stream>>>(
            w2t + (size_t)layer * DD * HH, nx, w2s);

        gemm_bf16_kernel<HH, DD, 1><<<dim3(DD / 256, MM / 256), 512, 0, stream>>>(
            h, w2s, bias2 + (size_t)layer * DD,
            nullptr, x, text, gxp);
    }

    upscan_kernel<<<BB, 256, 0, stream>>>(text, audio, pos, lens);
    upgather_kernel<<<MM, 128, 0, stream>>>(x, pos, lens, out);
}

// Round 17
// 633.305 us; speedup vs baseline: 1.0345x; 1.0345x over previous
//
#include <hip/hip_runtime.h>
#include <hip/hip_bf16.h>

#define BB 16
#define LL 2048
#define DD 512
#define HH 1024
#define NL 4
#define MM (BB*LL)   // 32768

typedef __attribute__((ext_vector_type(8))) short bh8;
typedef __attribute__((ext_vector_type(4))) float f4;
typedef __attribute__((ext_vector_type(4))) unsigned short us4;

typedef __attribute__((address_space(3))) unsigned int lds_u32;
typedef __attribute__((address_space(1))) const unsigned int glob_u32;

__device__ __forceinline__ void gld_lds16(const void* g, void* l) {
    __builtin_amdgcn_global_load_lds((glob_u32*)g, (lds_u32*)l, 16, 0, 0);
}

__device__ __forceinline__ unsigned short f2bf(float f) {
    unsigned int u = __float_as_uint(f);
    unsigned int r = (u + 0x7FFFu + ((u >> 16) & 1u)) >> 16;
    return (unsigned short)r;
}
__device__ __forceinline__ float bf2f(unsigned short u) {
    return __uint_as_float(((unsigned int)u) << 16);
}

// fast GELU (tanh form, abs err ~1e-4)
__device__ __forceinline__ float gelu_f(float v) {
    float y = 0.7978845608028654f * v * fmaf(0.044715f, v * v, 1.0f);
    float e = __expf(2.0f * y);
    float th = 1.0f - 2.0f * __builtin_amdgcn_rcpf(e + 1.0f);
    return 0.5f * v * (1.0f + th);
}

// ---------------- FREQS_CIS table [L, D]
__global__ __launch_bounds__(256) void freqs_kernel(float* __restrict__ fr) {
    int idx = blockIdx.x * 256 + threadIdx.x;
    int l = idx >> 8;
    int j = idx & 255;
    float f = exp2f(-(float)j * 0.051905126482615036f);  // log2(10000)/256
    float a = (float)l * f;
    fr[(size_t)l * DD + j]       = cosf(a);
    fr[(size_t)l * DD + 256 + j] = sinf(a);
}

// ---------------- weight transpose+convert: [NL][R][C] f32 -> [NL][C][R] bf16
__global__ __launch_bounds__(256) void wtrans_kernel(const float* __restrict__ w,
                                                     unsigned short* __restrict__ wt,
                                                     int R, int C) {
    __shared__ float ls[64][65];
    int layer = blockIdx.z;
    int tr = blockIdx.y;
    int tc = blockIdx.x;
    const float* src = w + (size_t)layer * R * C + (size_t)(tr * 64) * C + tc * 64;
    int t = threadIdx.x;
    #pragma unroll
    for (int s = 0; s < 4; s++) {
        int r = (t >> 4) + 16 * s, c = (t & 15) * 4;
        f4 v = *(const f4*)(src + (size_t)r * C + c);
        ls[r][c] = v.x; ls[r][c + 1] = v.y; ls[r][c + 2] = v.z; ls[r][c + 3] = v.w;
    }
    __syncthreads();
    unsigned short* dst = wt + (size_t)layer * R * C + (size_t)(tc * 64) * R + tr * 64;
    #pragma unroll
    for (int s = 0; s < 2; s++) {
        int idx = t + 256 * s;
        int c = idx >> 3;
        int r8 = (idx & 7) * 8;
        bh8 o;
        #pragma unroll
        for (int e = 0; e < 8; e++) o[e] = (short)f2bf(ls[r8 + e][c]);
        *(bh8*)(dst + (size_t)c * R + r8) = o;
    }
}

// ---------------- bias2[n] = pw2_b[n] + sum_k grn_b[k] * W2[k][n]
__global__ __launch_bounds__(256) void bias2_kernel(const float* __restrict__ pw2_b,
                                                    const float* __restrict__ grn_b,
                                                    const unsigned short* __restrict__ w2t,
                                                    float* __restrict__ bias2) {
    int layer = blockIdx.x;
    for (int n = threadIdx.x; n < DD; n += 256) {
        const unsigned short* wp = w2t + (size_t)layer * DD * HH + (size_t)n * HH;
        const float* gbp = grn_b + (size_t)layer * HH;
        float s = 0.f;
        for (int k8 = 0; k8 < HH; k8 += 8) {
            bh8 wv = *(const bh8*)(wp + k8);
            #pragma unroll
            for (int e = 0; e < 8; e++) s = fmaf(gbp[k8 + e], bf2f((unsigned short)wv[e]), s);
        }
        bias2[(size_t)layer * DD + n] = pw2_b[(size_t)layer * DD + n] + s;
    }
}

// ---------------- embedding + freqs + mask -> bf16 x
__global__ __launch_bounds__(64) void embed_kernel(const int* __restrict__ text,
                                                   const float* __restrict__ table,
                                                   const float* __restrict__ fr,
                                                   unsigned short* __restrict__ x) {
    int bid = blockIdx.x;            // b*L + l
    int t = threadIdx.x;             // 64 lanes, 8 ch each
    int l = bid & (LL - 1);
    int d0 = t * 8;
    int tok = text[bid] + 1;
    bh8 o;
    if (tok != 0) {
        const float* e = table + (size_t)tok * DD + d0;
        const float* f = fr + (size_t)l * DD + d0;
        #pragma unroll
        for (int k = 0; k < 8; k++) o[k] = (short)f2bf(e[k] + f[k]);
    } else {
        #pragma unroll
        for (int k = 0; k < 8; k++) o[k] = 0;
    }
    *(bh8*)(x + (size_t)bid * DD + d0) = o;
}

// ---------------- depthwise conv7 + bias + LayerNorm -> bf16 (x input is bf16)
#define CCH 16
__global__ __launch_bounds__(256) void conv_ln_kernel(const unsigned short* __restrict__ x,
                                                      const float* __restrict__ dw_w,
                                                      const float* __restrict__ dw_b,
                                                      const float* __restrict__ ln_g,
                                                      const float* __restrict__ ln_b,
                                                      unsigned short* __restrict__ xln) {
    const int t = threadIdx.x;
    const int lane = t & 63, wv = t >> 6;
    const int chunk = blockIdx.x * 4 + wv;
    const int row0 = chunk * CCH;
    const int l0 = row0 & (LL - 1);
    const int d0 = lane * 8;
    const unsigned short* xb = x + ((size_t)(row0 >> 11) * LL) * DD + d0;

    float w[7][8], cb[8], g[8], be[8];
    #pragma unroll
    for (int e = 0; e < 8; e++) {
        #pragma unroll
        for (int k = 0; k < 7; k++) w[k][e] = dw_w[(d0 + e) * 7 + k];
        cb[e] = dw_b[d0 + e];
        g[e]  = ln_g[d0 + e];
        be[e] = ln_b[d0 + e];
    }

    float ring[8][8];
    #pragma unroll
    for (int ii = 0; ii < 8; ii++) {
        int i = ii - 3;
        int s = i & 7;
        int l = l0 + i;
        bool ok = (unsigned)l < LL;
        if (ok) {
            bh8 v = *(const bh8*)(xb + (size_t)l * DD);
            #pragma unroll
            for (int e = 0; e < 8; e++) ring[s][e] = bf2f((unsigned short)v[e]);
        } else {
            #pragma unroll
            for (int e = 0; e < 8; e++) ring[s][e] = 0.f;
        }
    }

    #pragma unroll
    for (int r = 0; r < CCH; r++) {
        float acc[8];
        #pragma unroll
        for (int e = 0; e < 8; e++) acc[e] = cb[e];
        #pragma unroll
        for (int k = 0; k < 7; k++) {
            int s = (r + k - 3) & 7;
            #pragma unroll
            for (int e = 0; e < 8; e++) acc[e] = fmaf(w[k][e], ring[s][e], acc[e]);
        }
        if (r + 5 <= CCH + 2) {
            int s = (r + 5) & 7;
            int l = l0 + r + 5;
            bool ok = (unsigned)l < LL;
            if (ok) {
                bh8 v = *(const bh8*)(xb + (size_t)l * DD);
                #pragma unroll
                for (int e = 0; e < 8; e++) ring[s][e] = bf2f((unsigned short)v[e]);
            } else {
                #pragma unroll
                for (int e = 0; e < 8; e++) ring[s][e] = 0.f;
            }
        }
        float s1 = 0.f, s2 = 0.f;
        #pragma unroll
        for (int e = 0; e < 8; e++) { s1 += acc[e]; s2 = fmaf(acc[e], acc[e], s2); }
        #pragma unroll
        for (int off = 1; off <= 32; off <<= 1) {
            s1 += __shfl_xor(s1, off, 64);
            s2 += __shfl_xor(s2, off, 64);
        }
        float mu = s1 * (1.0f / DD);
        float var = s2 * (1.0f / DD) - mu * mu;
        float rstd = rsqrtf(var + 1e-6f);
        bh8 o;
        #pragma unroll
        for (int e = 0; e < 8; e++) o[e] = (short)f2bf((acc[e] - mu) * rstd * g[e] + be[e]);
        *(bh8*)(xln + (size_t)(row0 + r) * DD + d0) = o;
    }
}

// ---------------- bf16 MFMA GEMM: 256x256 tile, 8 waves (2Mx4N), BK=32, dbuf = 64KB LDS
// -> 2 blocks/CU. CORRECTED swizzle: sw(row) = (row>>1)&3 (even/odd lane pairs share a
// bank base; (row>>1)&3 spreads 8 lanes over 4 chunk slots = free 2-way aliasing).
// Read kq = ((lane>>4) ^ ((ln>>1)&3))*8; stage source col ((tid&3) ^ ((tid>>3)&3))*8.
// R9's provable drain-0 ledger (stage-all -> compute -> vmcnt(0)+barrier).
// MODE 0 (GEMM1): h = bf16(gelu(C+bias)); writes 64-row-block partials of sum(h^2) to aux
// MODE 1 (GEMM2): B = per-batch pre-scaled W2 (batch = m0>>11); epilogue stages C+bias as
//   f32 in LDS (4 passes of 64x256 = 64KB), coalesced us4 RMW on bf16 x.
template<int KDIM, int NDIM, int MODE>
__global__ __launch_bounds__(512) void gemm_bf16_kernel(const unsigned short* __restrict__ A,
                                                        const unsigned short* __restrict__ Bt,
                                                        const float* __restrict__ bias,
                                                        unsigned short* __restrict__ hout,
                                                        unsigned short* __restrict__ xio,
                                                        const int* __restrict__ text,
                                                        float* __restrict__ aux) {
    __shared__ unsigned short lsbuf[32768];    // 64KB: A dbuf (0..16383), B dbuf (16384..32767)
    const int tid = threadIdx.x;
    constexpr int NX = NDIM / 256;
    constexpr int NWG = NX * (MM / 256);
    constexpr int NT = KDIM / 32;
    const int id = blockIdx.y * NX + blockIdx.x;
    const int sw = (id & 7) * (NWG / 8) + (id >> 3);     // XCD-chunked (NWG%8==0)
    const int m0 = (sw / NX) * 256;
    const int n0 = (sw % NX) * 256;

    const int lane = tid & 63, wid = tid >> 6;
    const int wm = wid >> 2, wn = wid & 3;               // wave tile: 128 rows x 64 cols
    const int ln = lane & 15;
    const int kq = (((lane >> 4) ^ ((ln >> 1) & 3)) << 3);  // swizzled k offset (shorts)
    const int arow = (wm * 128 + ln) * 32;               // + i*512
    const int brow = (wn * 64 + ln) * 32;                // + j*512

    const int srow = tid >> 2;                           // 0..127
    const int scol = (((tid & 3) ^ ((tid >> 3) & 3)) << 3); // inverse-swizzled global col
    const int sdst = tid * 8;                            // LDS shorts (rows 0..127); +4096 hi
    const unsigned short* Asrc = A + ((size_t)m0 + srow) * KDIM + scol;
    const unsigned short* Bsrc;
    if constexpr (MODE == 0) Bsrc = Bt + ((size_t)n0 + srow) * KDIM + scol;
    else                     Bsrc = Bt + ((size_t)(m0 >> 11) * NDIM + n0 + srow) * KDIM + scol;

    f4 acc[8][4];
    #pragma unroll
    for (int i = 0; i < 8; i++)
        #pragma unroll
        for (int j = 0; j < 4; j++) acc[i][j] = (f4){0.f, 0.f, 0.f, 0.f};

#define LSA(bb) (lsbuf + (bb) * 8192)
#define LSB(bb) (lsbuf + 16384 + (bb) * 8192)
#define STG_ALL(bb, ko) do {                                                               \
    gld_lds16(Asrc + (ko), LSA(bb) + sdst);                                                \
    gld_lds16(Asrc + (size_t)128 * KDIM + (ko), LSA(bb) + 4096 + sdst);                    \
    gld_lds16(Bsrc + (ko), LSB(bb) + sdst);                                                \
    gld_lds16(Bsrc + (size_t)128 * KDIM + (ko), LSB(bb) + 4096 + sdst); } while (0)
#define BOUNDARY do { asm volatile("s_waitcnt vmcnt(0)" ::: "memory");                     \
    __builtin_amdgcn_s_barrier(); __builtin_amdgcn_sched_barrier(0); } while (0)

    STG_ALL(0, 0);
    BOUNDARY;

    for (int kt = 0; kt < NT; kt++) {
        const int cur = kt & 1;
        const bool more = (kt + 1 < NT);
        if (more) { STG_ALL(cur ^ 1, (kt + 1) * 32); }
        __builtin_amdgcn_sched_barrier(0);       // keep stage issues at top
        bh8 aF[8], bF[4];
        #pragma unroll
        for (int i = 0; i < 8; i++) aF[i] = *(bh8*)(LSA(cur) + arow + i * 512 + kq);
        #pragma unroll
        for (int j = 0; j < 4; j++) bF[j] = *(bh8*)(LSB(cur) + brow + j * 512 + kq);
        __builtin_amdgcn_s_setprio(1);
        #pragma unroll
        for (int i = 0; i < 8; i++)
            #pragma unroll
            for (int j = 0; j < 4; j++)
                acc[i][j] = __builtin_amdgcn_mfma_f32_16x16x32_bf16(aF[i], bF[j], acc[i][j], 0, 0, 0);
        __builtin_amdgcn_s_setprio(0);
        if (more) { BOUNDARY; }
    }
#undef STG_ALL
#undef BOUNDARY
#undef LSA
#undef LSB

    const int rowOff = (lane >> 4) * 4;
    const int colOff = ln;
    if constexpr (MODE == 0) {
        float sj0[4] = {0.f, 0.f, 0.f, 0.f};
        float sj1[4] = {0.f, 0.f, 0.f, 0.f};
        #pragma unroll
        for (int i = 0; i < 8; i++) {
            #pragma unroll
            for (int j = 0; j < 4; j++) {
                int n = n0 + wn * 64 + j * 16 + colOff;
                float bn = bias[n];
                #pragma unroll
                for (int r = 0; r < 4; r++) {
                    int m = m0 + wm * 128 + i * 16 + rowOff + r;
                    float v = gelu_f(acc[i][j][r] + bn);
                    hout[(size_t)m * NDIM + n] = f2bf(v);
                    if (i < 4) sj0[j] = fmaf(v, v, sj0[j]);
                    else       sj1[j] = fmaf(v, v, sj1[j]);
                }
            }
        }
        #pragma unroll
        for (int j = 0; j < 4; j++) {
            sj0[j] += __shfl_xor(sj0[j], 16, 64);
            sj0[j] += __shfl_xor(sj0[j], 32, 64);
            sj1[j] += __shfl_xor(sj1[j], 16, 64);
            sj1[j] += __shfl_xor(sj1[j], 32, 64);
        }
        if (lane < 16) {
            int rb = (m0 + wm * 128) >> 6;       // 64-row blocks
            #pragma unroll
            for (int j = 0; j < 4; j++) {
                aux[(size_t)rb * HH + n0 + wn * 64 + j * 16 + lane] = sj0[j];
                aux[(size_t)(rb + 1) * HH + n0 + wn * 64 + j * 16 + lane] = sj1[j];
            }
        }
    } else {
        // staged coalesced RMW epilogue: 4 passes of 64 rows x 256 cols f32 (64KB LDS)
        __syncthreads();                          // all waves done reading last K-tile
        float* cf = (float*)lsbuf;                // 64 x 256 f32 = 64KB
        #pragma unroll
        for (int p = 0; p < 4; p++) {
            const int half = p >> 1, qtr = p & 1;
            if (wm == half) {
                #pragma unroll
                for (int i = 0; i < 4; i++) {
                    int ii = qtr * 4 + i;
                    #pragma unroll
                    for (int j = 0; j < 4; j++) {
                        int lc = wn * 64 + j * 16 + colOff;
                        float bn = bias[n0 + lc];
                        #pragma unroll
                        for (int r = 0; r < 4; r++) {
                            int lr = ii * 16 + rowOff + r - qtr * 64;
                            cf[lr * 256 + lc] = acc[ii][j][r] + bn;
                        }
                    }
                }
            }
            __syncthreads();
            #pragma unroll
            for (int k = 0; k < 8; k++) {
                int ci = tid + 512 * k;           // 4096 chunks of 4 cols
                int row = ci >> 6, ch = ci & 63;
                int m = m0 + half * 128 + qtr * 64 + row;
                size_t gb = (size_t)m * NDIM + n0 + ch * 4;
                bool msk = (text[m] == -1);
                us4 xo = *(const us4*)(xio + gb);
                f4 c = *(const f4*)&cf[row * 256 + ch * 4];
                us4 onew;
                onew.x = msk ? 0 : f2bf(c.x + bf2f(xo.x));
                onew.y = msk ? 0 : f2bf(c.y + bf2f(xo.y));
                onew.z = msk ? 0 : f2bf(c.z + bf2f(xo.z));
                onew.w = msk ? 0 : f2bf(c.w + bf2f(xo.w));
                *(us4*)(xio + gb) = onew;
            }
            __syncthreads();
        }
    }
}

// ---------------- GRN stats: scale[b][ch] = 1 + gg[ch] * Nx[b][ch]
__global__ __launch_bounds__(256) void grn_stats_kernel(const float* __restrict__ gxp,
                                                        const float* __restrict__ gg,
                                                        float* __restrict__ scale) {
    int b = blockIdx.x, t = threadIdx.x;
    float g[4];
    float s = 0.f;
    #pragma unroll
    for (int e = 0; e < 4; e++) {
        int ch = t + e * 256;
        float acc = 0.f;
        #pragma unroll
        for (int rb = 0; rb < 32; rb++) acc += gxp[(size_t)(b * 32 + rb) * HH + ch];
        g[e] = sqrtf(acc);
        s += g[e];
    }
    #pragma unroll
    for (int off = 32; off > 0; off >>= 1) s += __shfl_down(s, off);
    __shared__ float rs[4];
    if ((t & 63) == 0) rs[t >> 6] = s;
    __syncthreads();
    float tot = rs[0] + rs[1] + rs[2] + rs[3];
    float mean = tot * (1.0f / HH);
    float inv = 1.0f / (mean + 1e-6f);
    #pragma unroll
    for (int e = 0; e < 4; e++) {
        int ch = t + e * 256;
        scale[(size_t)b * HH + ch] = fmaf(gg[ch], g[e] * inv, 1.0f);
    }
}

// ---------------- per-batch scaled W2: w2s[b][n][k] = bf16(scale[b][k] * w2t[n][k])
__global__ __launch_bounds__(256) void w2scale_kernel(const unsigned short* __restrict__ w2t,
                                                      const float* __restrict__ scale,
                                                      unsigned short* __restrict__ w2s) {
    int b = blockIdx.y;
    size_t idx = ((size_t)blockIdx.x * 256 + threadIdx.x) * 8;   // over DD*HH
    int k = (int)(idx & (HH - 1));
    bh8 w = *(const bh8*)(w2t + idx);
    f4 s0 = *(const f4*)(scale + (size_t)b * HH + k);
    f4 s1 = *(const f4*)(scale + (size_t)b * HH + k + 4);
    float sv[8] = {s0.x,s0.y,s0.z,s0.w,s1.x,s1.y,s1.z,s1.w};
    bh8 o;
    #pragma unroll
    for (int e = 0; e < 8; e++) o[e] = (short)f2bf(bf2f((unsigned short)w[e]) * sv[e]);
    *(bh8*)(w2s + (size_t)b * DD * HH + idx) = o;
}

// ---------------- upsample scan (wave-ballot scan: 2 barriers/chunk)
__global__ __launch_bounds__(256) void upscan_kernel(const int* __restrict__ text,
                                                     const int* __restrict__ audio,
                                                     int* __restrict__ pos,
                                                     int* __restrict__ lens) {
    int b = blockIdx.x, t = threadIdx.x;
    int lane = t & 63, wv = t >> 6;
    __shared__ int wt[4], wa[4];
    int voff = 0, aoff = 0;
    for (int c = 0; c < LL / 256; c++) {
        int l = c * 256 + t;
        int am = audio[(size_t)b * LL + l];
        int tv = text[(size_t)b * LL + l];
        int valid = (am != 0 && tv != -1) ? 1 : 0;
        unsigned long long mv = __ballot(valid);
        unsigned long long ma = __ballot(am != 0);
        if (lane == 0) { wt[wv] = __popcll(mv); wa[wv] = __popcll(ma); }
        __syncthreads();
        int pre = 0;
        #pragma unroll
        for (int w = 0; w < 4; w++) if (w < wv) pre += wt[w];
        int incl = pre + (int)__popcll(mv << (63 - lane));   // bits 0..lane
        if (valid) pos[(size_t)b * LL + voff + incl - 1] = l;
        int bt = wt[0] + wt[1] + wt[2] + wt[3];
        int ba = wa[0] + wa[1] + wa[2] + wa[3];
        __syncthreads();
        voff += bt;
        aoff += ba;
    }
    if (t == 0) { lens[b * 2] = aoff; lens[b * 2 + 1] = voff; }
    for (int i = voff + t; i < LL; i += 256) pos[(size_t)b * LL + i] = LL - 1;
}

// ---------------- upsample gather (x bf16 -> out f32; 128 threads x 4 elems)
__global__ __launch_bounds__(128) void upgather_kernel(const unsigned short* __restrict__ x,
                                                       const int* __restrict__ pos,
                                                       const int* __restrict__ lens,
                                                       float* __restrict__ out) {
    int bid = blockIdx.x;
    int b = bid >> 11;
    int p = bid & (LL - 1);
    int t = threadIdx.x;
    int alen = lens[b * 2], vlen = lens[b * 2 + 1];
    f4 v = {0.f, 0.f, 0.f, 0.f};
    if (p < alen && vlen > 0) {
        int vl = vlen < 1 ? 1 : vlen;
        int base = alen / vl, rem = alen % vl;
        int cut = (vl - rem) * base;
        int j;
        if (p < cut) j = p / (base < 1 ? 1 : base);
        else j = (vl - rem) + (p - cut) / (base + 1);
        j = j < 0 ? 0 : (j > LL - 1 ? LL - 1 : j);
        int s = pos[(size_t)b * LL + j];
        s = s < 0 ? 0 : (s > LL - 1 ? LL - 1 : s);
        us4 u = *(const us4*)(x + ((size_t)b * LL + s) * DD + t * 4);
        v.x = bf2f(u.x); v.y = bf2f(u.y); v.z = bf2f(u.z); v.w = bf2f(u.w);
    }
    *(f4*)(out + (size_t)bid * DD + t * 4) = v;
}

// ---------------- workspace layout (bytes)
#define OFF_FREQS  ((size_t)0)
#define OFF_X      (OFF_FREQS + (size_t)LL * DD * 4)          // 4 MB (freqs f32)
#define OFF_XLN    (OFF_X + (size_t)MM * DD * 2)              // +32 MB (x bf16)
#define OFF_H      (OFF_XLN + (size_t)MM * DD * 2)            // +32 MB
#define OFF_W1T    (OFF_H + (size_t)MM * HH * 2)              // +64 MB
#define OFF_W2T    (OFF_W1T + (size_t)NL * HH * DD * 2)       // +4 MB
#define OFF_GXP    (OFF_W2T + (size_t)NL * DD * HH * 2)       // +4 MB
#define OFF_NX     (OFF_GXP + (size_t)512 * HH * 4)           // +2 MB
#define OFF_B2     (OFF_NX + (size_t)BB * HH * 4)             // +64 KB
#define OFF_POS    (OFF_B2 + (size_t)NL * DD * 4)             // +8 KB
#define OFF_LENS   (OFF_POS + (size_t)BB * LL * 4)            // +128 KB
// w2s (16 MB) overlays xln's region (xln dead between GEMM1(layer) and conv_ln(layer+1))
#define OFF_W2S    OFF_XLN

extern "C" void kernel_launch(void* const* d_in, const int* in_sizes, int n_in,
                              void* d_out, int out_size, void* d_ws, size_t ws_size,
                              hipStream_t stream) {
    const int*   text  = (const int*)d_in[0];
    const int*   audio = (const int*)d_in[1];
    const float* table = (const float*)d_in[3];
    const float* dw_w  = (const float*)d_in[4];
    const float* dw_b  = (const float*)d_in[5];
    const float* ln_g  = (const float*)d_in[6];
    const float* ln_b  = (const float*)d_in[7];
    const float* pw1_w = (const float*)d_in[8];
    const float* pw1_b = (const float*)d_in[9];
    const float* grn_g = (const float*)d_in[10];
    const float* grn_b = (const float*)d_in[11];
    const float* pw2_w = (const float*)d_in[12];
    const float* pw2_b = (const float*)d_in[13];
    float* out = (float*)d_out;

    char* ws = (char*)d_ws;
    float*          freqs = (float*)(ws + OFF_FREQS);
    unsigned short* x     = (unsigned short*)(ws + OFF_X);
    unsigned short* xln   = (unsigned short*)(ws + OFF_XLN);
    unsigned short* h     = (unsigned short*)(ws + OFF_H);
    unsigned short* w1t   = (unsigned short*)(ws + OFF_W1T);
    unsigned short* w2t   = (unsigned short*)(ws + OFF_W2T);
    unsigned short* w2s   = (unsigned short*)(ws + OFF_W2S);
    float*          gxp   = (float*)(ws + OFF_GXP);
    float*          nx    = (float*)(ws + OFF_NX);
    float*          bias2 = (float*)(ws + OFF_B2);
    int*            pos   = (int*)(ws + OFF_POS);
    int*            lens  = (int*)(ws + OFF_LENS);

    freqs_kernel<<<LL, 256, 0, stream>>>(freqs);
    wtrans_kernel<<<dim3(HH / 64, DD / 64, NL), 256, 0, stream>>>(pw1_w, w1t, DD, HH);
    wtrans_kernel<<<dim3(DD / 64, HH / 64, NL), 256, 0, stream>>>(pw2_w, w2t, HH, DD);
    bias2_kernel<<<NL, 256, 0, stream>>>(pw2_b, grn_b, w2t, bias2);
    embed_kernel<<<MM, 64, 0, stream>>>(text, table, freqs, x);

    for (int layer = 0; layer < NL; layer++) {
        conv_ln_kernel<<<MM / (4 * CCH), 256, 0, stream>>>(x,
            dw_w + (size_t)layer * DD * 7, dw_b + (size_t)layer * DD,
            ln_g + (size_t)layer * DD, ln_b + (size_t)layer * DD, xln);

        gemm_bf16_kernel<DD, HH, 0><<<dim3(HH / 256, MM / 256), 512, 0, stream>>>(
            xln, w1t + (size_t)layer * HH * DD, pw1_b + (size_t)layer * HH,
            h, nullptr, nullptr, gxp);

        grn_stats_kernel<<<BB, 256, 0, stream>>>(gxp, grn_g + (size_t)layer * HH, nx);

        w2scale_kernel<<<dim3(DD * HH / (256 * 8), BB), 256, 0, stream>>>(
            w2t + (size_t)layer * DD * HH, nx, w2s);

        gemm_bf16_kernel<HH, DD, 1><<<dim3(DD / 256, MM / 256), 512, 0, stream>>>(
            h, w2s, bias2 + (size_t)layer * DD,
            nullptr, x, text, gxp);
    }

    upscan_kernel<<<BB, 256, 0, stream>>>(text, audio, pos, lens);
    upgather_kernel<<<MM, 128, 0, stream>>>(x, pos, lens, out);
}

// Round 18
// 603.682 us; speedup vs baseline: 1.0852x; 1.0491x over previous
//
#include <hip/hip_runtime.h>
#include <hip/hip_bf16.h>

#define BB 16
#define LL 2048
#define DD 512
#define HH 1024
#define NL 4
#define MM (BB*LL)   // 32768

typedef __attribute__((ext_vector_type(8))) short bh8;
typedef __attribute__((ext_vector_type(4))) float f4;
typedef __attribute__((ext_vector_type(4))) unsigned short us4;

typedef __attribute__((address_space(3))) unsigned int lds_u32;
typedef __attribute__((address_space(1))) const unsigned int glob_u32;

__device__ __forceinline__ void gld_lds16(const void* g, void* l) {
    __builtin_amdgcn_global_load_lds((glob_u32*)g, (lds_u32*)l, 16, 0, 0);
}

__device__ __forceinline__ unsigned short f2bf(float f) {
    unsigned int u = __float_as_uint(f);
    unsigned int r = (u + 0x7FFFu + ((u >> 16) & 1u)) >> 16;
    return (unsigned short)r;
}
__device__ __forceinline__ float bf2f(unsigned short u) {
    return __uint_as_float(((unsigned int)u) << 16);
}

// fast GELU (tanh form, abs err ~1e-4)
__device__ __forceinline__ float gelu_f(float v) {
    float y = 0.7978845608028654f * v * fmaf(0.044715f, v * v, 1.0f);
    float e = __expf(2.0f * y);
    float th = 1.0f - 2.0f * __builtin_amdgcn_rcpf(e + 1.0f);
    return 0.5f * v * (1.0f + th);
}

// ---------------- FREQS_CIS table [L, D]
__global__ __launch_bounds__(256) void freqs_kernel(float* __restrict__ fr) {
    int idx = blockIdx.x * 256 + threadIdx.x;
    int l = idx >> 8;
    int j = idx & 255;
    float f = exp2f(-(float)j * 0.051905126482615036f);  // log2(10000)/256
    float a = (float)l * f;
    fr[(size_t)l * DD + j]       = cosf(a);
    fr[(size_t)l * DD + 256 + j] = sinf(a);
}

// ---------------- weight transpose+convert: [NL][R][C] f32 -> [NL][C][R] bf16
__global__ __launch_bounds__(256) void wtrans_kernel(const float* __restrict__ w,
                                                     unsigned short* __restrict__ wt,
                                                     int R, int C) {
    __shared__ float ls[64][65];
    int layer = blockIdx.z;
    int tr = blockIdx.y;
    int tc = blockIdx.x;
    const float* src = w + (size_t)layer * R * C + (size_t)(tr * 64) * C + tc * 64;
    int t = threadIdx.x;
    #pragma unroll
    for (int s = 0; s < 4; s++) {
        int r = (t >> 4) + 16 * s, c = (t & 15) * 4;
        f4 v = *(const f4*)(src + (size_t)r * C + c);
        ls[r][c] = v.x; ls[r][c + 1] = v.y; ls[r][c + 2] = v.z; ls[r][c + 3] = v.w;
    }
    __syncthreads();
    unsigned short* dst = wt + (size_t)layer * R * C + (size_t)(tc * 64) * R + tr * 64;
    #pragma unroll
    for (int s = 0; s < 2; s++) {
        int idx = t + 256 * s;
        int c = idx >> 3;
        int r8 = (idx & 7) * 8;
        bh8 o;
        #pragma unroll
        for (int e = 0; e < 8; e++) o[e] = (short)f2bf(ls[r8 + e][c]);
        *(bh8*)(dst + (size_t)c * R + r8) = o;
    }
}

// ---------------- bias2[n] = pw2_b[n] + sum_k grn_b[k] * W2[k][n]
__global__ __launch_bounds__(256) void bias2_kernel(const float* __restrict__ pw2_b,
                                                    const float* __restrict__ grn_b,
                                                    const unsigned short* __restrict__ w2t,
                                                    float* __restrict__ bias2) {
    int layer = blockIdx.x;
    for (int n = threadIdx.x; n < DD; n += 256) {
        const unsigned short* wp = w2t + (size_t)layer * DD * HH + (size_t)n * HH;
        const float* gbp = grn_b + (size_t)layer * HH;
        float s = 0.f;
        for (int k8 = 0; k8 < HH; k8 += 8) {
            bh8 wv = *(const bh8*)(wp + k8);
            #pragma unroll
            for (int e = 0; e < 8; e++) s = fmaf(gbp[k8 + e], bf2f((unsigned short)wv[e]), s);
        }
        bias2[(size_t)layer * DD + n] = pw2_b[(size_t)layer * DD + n] + s;
    }
}

// ---------------- embedding + freqs + mask -> bf16 x
__global__ __launch_bounds__(64) void embed_kernel(const int* __restrict__ text,
                                                   const float* __restrict__ table,
                                                   const float* __restrict__ fr,
                                                   unsigned short* __restrict__ x) {
    int bid = blockIdx.x;            // b*L + l
    int t = threadIdx.x;             // 64 lanes, 8 ch each
    int l = bid & (LL - 1);
    int d0 = t * 8;
    int tok = text[bid] + 1;
    bh8 o;
    if (tok != 0) {
        const float* e = table + (size_t)tok * DD + d0;
        const float* f = fr + (size_t)l * DD + d0;
        #pragma unroll
        for (int k = 0; k < 8; k++) o[k] = (short)f2bf(e[k] + f[k]);
    } else {
        #pragma unroll
        for (int k = 0; k < 8; k++) o[k] = 0;
    }
    *(bh8*)(x + (size_t)bid * DD + d0) = o;
}

// ---------------- depthwise conv7 + bias + LayerNorm -> bf16 (x input is bf16)
#define CCH 16
__global__ __launch_bounds__(256) void conv_ln_kernel(const unsigned short* __restrict__ x,
                                                      const float* __restrict__ dw_w,
                                                      const float* __restrict__ dw_b,
                                                      const float* __restrict__ ln_g,
                                                      const float* __restrict__ ln_b,
                                                      unsigned short* __restrict__ xln) {
    const int t = threadIdx.x;
    const int lane = t & 63, wv = t >> 6;
    const int chunk = blockIdx.x * 4 + wv;
    const int row0 = chunk * CCH;
    const int l0 = row0 & (LL - 1);
    const int d0 = lane * 8;
    const unsigned short* xb = x + ((size_t)(row0 >> 11) * LL) * DD + d0;

    float w[7][8], cb[8], g[8], be[8];
    #pragma unroll
    for (int e = 0; e < 8; e++) {
        #pragma unroll
        for (int k = 0; k < 7; k++) w[k][e] = dw_w[(d0 + e) * 7 + k];
        cb[e] = dw_b[d0 + e];
        g[e]  = ln_g[d0 + e];
        be[e] = ln_b[d0 + e];
    }

    float ring[8][8];
    #pragma unroll
    for (int ii = 0; ii < 8; ii++) {
        int i = ii - 3;
        int s = i & 7;
        int l = l0 + i;
        bool ok = (unsigned)l < LL;
        if (ok) {
            bh8 v = *(const bh8*)(xb + (size_t)l * DD);
            #pragma unroll
            for (int e = 0; e < 8; e++) ring[s][e] = bf2f((unsigned short)v[e]);
        } else {
            #pragma unroll
            for (int e = 0; e < 8; e++) ring[s][e] = 0.f;
        }
    }

    #pragma unroll
    for (int r = 0; r < CCH; r++) {
        float acc[8];
        #pragma unroll
        for (int e = 0; e < 8; e++) acc[e] = cb[e];
        #pragma unroll
        for (int k = 0; k < 7; k++) {
            int s = (r + k - 3) & 7;
            #pragma unroll
            for (int e = 0; e < 8; e++) acc[e] = fmaf(w[k][e], ring[s][e], acc[e]);
        }
        if (r + 5 <= CCH + 2) {
            int s = (r + 5) & 7;
            int l = l0 + r + 5;
            bool ok = (unsigned)l < LL;
            if (ok) {
                bh8 v = *(const bh8*)(xb + (size_t)l * DD);
                #pragma unroll
                for (int e = 0; e < 8; e++) ring[s][e] = bf2f((unsigned short)v[e]);
            } else {
                #pragma unroll
                for (int e = 0; e < 8; e++) ring[s][e] = 0.f;
            }
        }
        float s1 = 0.f, s2 = 0.f;
        #pragma unroll
        for (int e = 0; e < 8; e++) { s1 += acc[e]; s2 = fmaf(acc[e], acc[e], s2); }
        #pragma unroll
        for (int off = 1; off <= 32; off <<= 1) {
            s1 += __shfl_xor(s1, off, 64);
            s2 += __shfl_xor(s2, off, 64);
        }
        float mu = s1 * (1.0f / DD);
        float var = s2 * (1.0f / DD) - mu * mu;
        float rstd = rsqrtf(var + 1e-6f);
        bh8 o;
        #pragma unroll
        for (int e = 0; e < 8; e++) o[e] = (short)f2bf((acc[e] - mu) * rstd * g[e] + be[e]);
        *(bh8*)(xln + (size_t)(row0 + r) * DD + d0) = o;
    }
}

// ---------------- bf16 MFMA GEMM: 256x256 tile, 8 waves (2Mx4N), BK=64.
// Provably-correct 2-phase double-buffer (R9). XOR-swizzled LDS, XCD swizzle, setprio.
// MODE 0 (GEMM1): h = bf16(gelu(C+bias)); writes 64-row-block partials of sum(h^2) to aux
// MODE 1 (GEMM2): B is per-batch pre-scaled W2 (batch = m0>>11);
//   epilogue: stage C+bias as f32 in LDS (2 half-passes of 128 rows), then all 512
//   threads do coalesced us4 RMW on bf16 x: x = mask ? 0 : bf16(C + bias + f32(x)).
template<int KDIM, int NDIM, int MODE>
__global__ __launch_bounds__(512) void gemm_bf16_kernel(const unsigned short* __restrict__ A,
                                                        const unsigned short* __restrict__ Bt,
                                                        const float* __restrict__ bias,
                                                        unsigned short* __restrict__ hout,
                                                        unsigned short* __restrict__ xio,
                                                        const int* __restrict__ text,
                                                        float* __restrict__ aux) {
    __shared__ unsigned short lsbuf[65536];    // 128KB: A dbuf (0..32767), B dbuf (32768..65535)
    const int tid = threadIdx.x;
    constexpr int NX = NDIM / 256;
    constexpr int NWG = NX * (MM / 256);
    constexpr int NT = KDIM / 64;
    const int id = blockIdx.y * NX + blockIdx.x;
    const int sw = (id & 7) * (NWG / 8) + (id >> 3);     // XCD-chunked (NWG%8==0)
    const int m0 = (sw / NX) * 256;
    const int n0 = (sw % NX) * 256;

    const int lane = tid & 63, wid = tid >> 6;
    const int wm = wid >> 2, wn = wid & 3;               // wave tile: 128 rows x 64 cols
    const int ln = lane & 15;
    const int kq0 = ((lane >> 4) * 8) ^ ((lane & 7) << 3);
    const int kq1 = (32 + (lane >> 4) * 8) ^ ((lane & 7) << 3);
    const int arow = (wm * 128 + ln) * 64;               // + i*1024
    const int brow = (wn * 64 + ln) * 64;                // + j*1024

    const int srow = tid >> 3;
    const int scol = ((tid & 7) ^ (srow & 7)) << 3;      // inverse-swizzled global col (shorts)
    const int sdst = tid * 8;                            // LDS dest (shorts), +4096 for q=1
    const unsigned short* Asrc = A + ((size_t)m0 + srow) * KDIM + scol;
    const unsigned short* Bsrc;
    if constexpr (MODE == 0) Bsrc = Bt + ((size_t)n0 + srow) * KDIM + scol;
    else                     Bsrc = Bt + ((size_t)(m0 >> 11) * NDIM + n0 + srow) * KDIM + scol;

    f4 acc[8][4];
    #pragma unroll
    for (int i = 0; i < 8; i++)
        #pragma unroll
        for (int j = 0; j < 4; j++) acc[i][j] = (f4){0.f, 0.f, 0.f, 0.f};

#define LSA(bb) (lsbuf + (bb) * 16384)
#define LSB(bb) (lsbuf + 32768 + (bb) * 16384)
#define STG_ALL(bb, ko) do { _Pragma("unroll") for (int h = 0; h < 2; h++) {               \
    gld_lds16(Asrc + (size_t)(h * 128) * KDIM + (ko), LSA(bb) + h * 8192 + sdst);          \
    gld_lds16(Asrc + (size_t)(h * 128 + 64) * KDIM + (ko), LSA(bb) + h * 8192 + 4096 + sdst); \
    gld_lds16(Bsrc + (size_t)(h * 128) * KDIM + (ko), LSB(bb) + h * 8192 + sdst);          \
    gld_lds16(Bsrc + (size_t)(h * 128 + 64) * KDIM + (ko), LSB(bb) + h * 8192 + 4096 + sdst); } } while (0)
#define BOUNDARY do { asm volatile("s_waitcnt vmcnt(0)" ::: "memory");                     \
    __builtin_amdgcn_s_barrier(); __builtin_amdgcn_sched_barrier(0); } while (0)
#define RD_A03 do { _Pragma("unroll") for (int i = 0; i < 4; i++) {                        \
    aF[i][0] = *(bh8*)(LSA(cur) + arow + i * 1024 + kq0);                                  \
    aF[i][1] = *(bh8*)(LSA(cur) + arow + i * 1024 + kq1); } } while (0)
#define RD_A47 do { _Pragma("unroll") for (int i = 0; i < 4; i++) {                        \
    aF[i][0] = *(bh8*)(LSA(cur) + arow + (i + 4) * 1024 + kq0);                            \
    aF[i][1] = *(bh8*)(LSA(cur) + arow + (i + 4) * 1024 + kq1); } } while (0)
#define RD_B01 do { _Pragma("unroll") for (int j = 0; j < 2; j++) {                        \
    b0F[j][0] = *(bh8*)(LSB(cur) + brow + j * 1024 + kq0);                                 \
    b0F[j][1] = *(bh8*)(LSB(cur) + brow + j * 1024 + kq1); } } while (0)
#define RD_B23 do { _Pragma("unroll") for (int j = 0; j < 2; j++) {                        \
    b1F[j][0] = *(bh8*)(LSB(cur) + brow + (j + 2) * 1024 + kq0);                           \
    b1F[j][1] = *(bh8*)(LSB(cur) + brow + (j + 2) * 1024 + kq1); } } while (0)
#define MFMA_Q(i0, j0, bf) do { __builtin_amdgcn_s_setprio(1);                             \
    _Pragma("unroll") for (int i = 0; i < 4; i++)                                          \
    _Pragma("unroll") for (int j = 0; j < 2; j++) {                                        \
        acc[i + i0][j + j0] = __builtin_amdgcn_mfma_f32_16x16x32_bf16(aF[i][0], bf[j][0], acc[i + i0][j + j0], 0, 0, 0); \
        acc[i + i0][j + j0] = __builtin_amdgcn_mfma_f32_16x16x32_bf16(aF[i][1], bf[j][1], acc[i + i0][j + j0], 0, 0, 0); } \
    __builtin_amdgcn_s_setprio(0); } while (0)

    STG_ALL(0, 0);
    BOUNDARY;

    bh8 aF[4][2], b0F[2][2], b1F[2][2];
    for (int kt = 0; kt < NT; kt++) {
        const int cur = kt & 1, nb = cur ^ 1;
        const bool more = (kt + 1 < NT);
        if (more) { STG_ALL(nb, (kt + 1) * 64); }
        __builtin_amdgcn_sched_barrier(0);       // keep stage issues at top
        RD_A03; RD_B01;
        MFMA_Q(0, 0, b0F);
        RD_B23;
        MFMA_Q(0, 2, b1F);
        RD_A47;
        MFMA_Q(4, 2, b1F);
        MFMA_Q(4, 0, b0F);
        if (more) { BOUNDARY; }
    }
#undef STG_ALL
#undef BOUNDARY
#undef RD_A03
#undef RD_A47
#undef RD_B01
#undef RD_B23
#undef MFMA_Q
#undef LSA
#undef LSB

    const int rowOff = (lane >> 4) * 4;
    const int colOff = ln;
    if constexpr (MODE == 0) {
        float sj0[4] = {0.f, 0.f, 0.f, 0.f};
        float sj1[4] = {0.f, 0.f, 0.f, 0.f};
        #pragma unroll
        for (int i = 0; i < 8; i++) {
            #pragma unroll
            for (int j = 0; j < 4; j++) {
                int n = n0 + wn * 64 + j * 16 + colOff;
                float bn = bias[n];
                #pragma unroll
                for (int r = 0; r < 4; r++) {
                    int m = m0 + wm * 128 + i * 16 + rowOff + r;
                    float v = gelu_f(acc[i][j][r] + bn);
                    hout[(size_t)m * NDIM + n] = f2bf(v);
                    if (i < 4) sj0[j] = fmaf(v, v, sj0[j]);
                    else       sj1[j] = fmaf(v, v, sj1[j]);
                }
            }
        }
        #pragma unroll
        for (int j = 0; j < 4; j++) {
            sj0[j] += __shfl_xor(sj0[j], 16, 64);
            sj0[j] += __shfl_xor(sj0[j], 32, 64);
            sj1[j] += __shfl_xor(sj1[j], 16, 64);
            sj1[j] += __shfl_xor(sj1[j], 32, 64);
        }
        if (lane < 16) {
            int rb = (m0 + wm * 128) >> 6;       // 64-row blocks
            #pragma unroll
            for (int j = 0; j < 4; j++) {
                aux[(size_t)rb * HH + n0 + wn * 64 + j * 16 + lane] = sj0[j];
                aux[(size_t)(rb + 1) * HH + n0 + wn * 64 + j * 16 + lane] = sj1[j];
            }
        }
    } else {
        // staged coalesced RMW epilogue
        __syncthreads();                          // all waves done reading last K-tile
        float* cf = (float*)lsbuf;                // 128 x 256 f32 = 128KB
        #pragma unroll
        for (int half = 0; half < 2; half++) {
            if (wm == half) {
                #pragma unroll
                for (int i = 0; i < 8; i++)
                    #pragma unroll
                    for (int j = 0; j < 4; j++) {
                        int lc = wn * 64 + j * 16 + colOff;
                        float bn = bias[n0 + lc];
                        #pragma unroll
                        for (int r = 0; r < 4; r++) {
                            int lr = i * 16 + rowOff + r;
                            cf[lr * 256 + lc] = acc[i][j][r] + bn;
                        }
                    }
            }
            __syncthreads();
            #pragma unroll
            for (int k = 0; k < 16; k++) {
                int ci = tid + 512 * k;           // 8192 chunks of 4 cols
                int row = ci >> 6, ch = ci & 63;
                int m = m0 + half * 128 + row;
                size_t gb = (size_t)m * NDIM + n0 + ch * 4;
                bool msk = (text[m] == -1);
                us4 xo = *(const us4*)(xio + gb);
                f4 c = *(const f4*)&cf[row * 256 + ch * 4];
                us4 onew;
                onew.x = msk ? 0 : f2bf(c.x + bf2f(xo.x));
                onew.y = msk ? 0 : f2bf(c.y + bf2f(xo.y));
                onew.z = msk ? 0 : f2bf(c.z + bf2f(xo.z));
                onew.w = msk ? 0 : f2bf(c.w + bf2f(xo.w));
                *(us4*)(xio + gb) = onew;
            }
            __syncthreads();
        }
    }
}

// ---------------- GRN stats: scale[b][ch] = 1 + gg[ch] * Nx[b][ch]
__global__ __launch_bounds__(256) void grn_stats_kernel(const float* __restrict__ gxp,
                                                        const float* __restrict__ gg,
                                                        float* __restrict__ scale) {
    int b = blockIdx.x, t = threadIdx.x;
    float g[4];
    float s = 0.f;
    #pragma unroll
    for (int e = 0; e < 4; e++) {
        int ch = t + e * 256;
        float acc = 0.f;
        #pragma unroll
        for (int rb = 0; rb < 32; rb++) acc += gxp[(size_t)(b * 32 + rb) * HH + ch];
        g[e] = sqrtf(acc);
        s += g[e];
    }
    #pragma unroll
    for (int off = 32; off > 0; off >>= 1) s += __shfl_down(s, off);
    __shared__ float rs[4];
    if ((t & 63) == 0) rs[t >> 6] = s;
    __syncthreads();
    float tot = rs[0] + rs[1] + rs[2] + rs[3];
    float mean = tot * (1.0f / HH);
    float inv = 1.0f / (mean + 1e-6f);
    #pragma unroll
    for (int e = 0; e < 4; e++) {
        int ch = t + e * 256;
        scale[(size_t)b * HH + ch] = fmaf(gg[ch], g[e] * inv, 1.0f);
    }
}

// ---------------- per-batch scaled W2: w2s[b][n][k] = bf16(scale[b][k] * w2t[n][k])
__global__ __launch_bounds__(256) void w2scale_kernel(const unsigned short* __restrict__ w2t,
                                                      const float* __restrict__ scale,
                                                      unsigned short* __restrict__ w2s) {
    int b = blockIdx.y;
    size_t idx = ((size_t)blockIdx.x * 256 + threadIdx.x) * 8;   // over DD*HH
    int k = (int)(idx & (HH - 1));
    bh8 w = *(const bh8*)(w2t + idx);
    f4 s0 = *(const f4*)(scale + (size_t)b * HH + k);
    f4 s1 = *(const f4*)(scale + (size_t)b * HH + k + 4);
    float sv[8] = {s0.x,s0.y,s0.z,s0.w,s1.x,s1.y,s1.z,s1.w};
    bh8 o;
    #pragma unroll
    for (int e = 0; e < 8; e++) o[e] = (short)f2bf(bf2f((unsigned short)w[e]) * sv[e]);
    *(bh8*)(w2s + (size_t)b * DD * HH + idx) = o;
}

// ---------------- upsample scan (wave-ballot scan: 2 barriers/chunk)
__global__ __launch_bounds__(256) void upscan_kernel(const int* __restrict__ text,
                                                     const int* __restrict__ audio,
                                                     int* __restrict__ pos,
                                                     int* __restrict__ lens) {
    int b = blockIdx.x, t = threadIdx.x;
    int lane = t & 63, wv = t >> 6;
    __shared__ int wt[4], wa[4];
    int voff = 0, aoff = 0;
    for (int c = 0; c < LL / 256; c++) {
        int l = c * 256 + t;
        int am = audio[(size_t)b * LL + l];
        int tv = text[(size_t)b * LL + l];
        int valid = (am != 0 && tv != -1) ? 1 : 0;
        unsigned long long mv = __ballot(valid);
        unsigned long long ma = __ballot(am != 0);
        if (lane == 0) { wt[wv] = __popcll(mv); wa[wv] = __popcll(ma); }
        __syncthreads();
        int pre = 0;
        #pragma unroll
        for (int w = 0; w < 4; w++) if (w < wv) pre += wt[w];
        int incl = pre + (int)__popcll(mv << (63 - lane));   // bits 0..lane
        if (valid) pos[(size_t)b * LL + voff + incl - 1] = l;
        int bt = wt[0] + wt[1] + wt[2] + wt[3];
        int ba = wa[0] + wa[1] + wa[2] + wa[3];
        __syncthreads();
        voff += bt;
        aoff += ba;
    }
    if (t == 0) { lens[b * 2] = aoff; lens[b * 2 + 1] = voff; }
    for (int i = voff + t; i < LL; i += 256) pos[(size_t)b * LL + i] = LL - 1;
}

// ---------------- upsample gather (x bf16 -> out f32; 128 threads x 4 elems)
__global__ __launch_bounds__(128) void upgather_kernel(const unsigned short* __restrict__ x,
                                                       const int* __restrict__ pos,
                                                       const int* __restrict__ lens,
                                                       float* __restrict__ out) {
    int bid = blockIdx.x;
    int b = bid >> 11;
    int p = bid & (LL - 1);
    int t = threadIdx.x;
    int alen = lens[b * 2], vlen = lens[b * 2 + 1];
    f4 v = {0.f, 0.f, 0.f, 0.f};
    if (p < alen && vlen > 0) {
        int vl = vlen < 1 ? 1 : vlen;
        int base = alen / vl, rem = alen % vl;
        int cut = (vl - rem) * base;
        int j;
        if (p < cut) j = p / (base < 1 ? 1 : base);
        else j = (vl - rem) + (p - cut) / (base + 1);
        j = j < 0 ? 0 : (j > LL - 1 ? LL - 1 : j);
        int s = pos[(size_t)b * LL + j];
        s = s < 0 ? 0 : (s > LL - 1 ? LL - 1 : s);
        us4 u = *(const us4*)(x + ((size_t)b * LL + s) * DD + t * 4);
        v.x = bf2f(u.x); v.y = bf2f(u.y); v.z = bf2f(u.z); v.w = bf2f(u.w);
    }
    *(f4*)(out + (size_t)bid * DD + t * 4) = v;
}

// ---------------- workspace layout (bytes)
#define OFF_FREQS  ((size_t)0)
#define OFF_X      (OFF_FREQS + (size_t)LL * DD * 4)          // 4 MB (freqs f32)
#define OFF_XLN    (OFF_X + (size_t)MM * DD * 2)              // +32 MB (x bf16)
#define OFF_H      (OFF_XLN + (size_t)MM * DD * 2)            // +32 MB
#define OFF_W1T    (OFF_H + (size_t)MM * HH * 2)              // +64 MB
#define OFF_W2T    (OFF_W1T + (size_t)NL * HH * DD * 2)       // +4 MB
#define OFF_GXP    (OFF_W2T + (size_t)NL * DD * HH * 2)       // +4 MB
#define OFF_NX     (OFF_GXP + (size_t)512 * HH * 4)           // +2 MB
#define OFF_B2     (OFF_NX + (size_t)BB * HH * 4)             // +64 KB
#define OFF_POS    (OFF_B2 + (size_t)NL * DD * 4)             // +8 KB
#define OFF_LENS   (OFF_POS + (size_t)BB * LL * 4)            // +128 KB
// w2s (16 MB) overlays xln's region (xln dead between GEMM1(layer) and conv_ln(layer+1))
#define OFF_W2S    OFF_XLN

extern "C" void kernel_launch(void* const* d_in, const int* in_sizes, int n_in,
                              void* d_out, int out_size, void* d_ws, size_t ws_size,
                              hipStream_t stream) {
    const int*   text  = (const int*)d_in[0];
    const int*   audio = (const int*)d_in[1];
    const float* table = (const float*)d_in[3];
    const float* dw_w  = (const float*)d_in[4];
    const float* dw_b  = (const float*)d_in[5];
    const float* ln_g  = (const float*)d_in[6];
    const float* ln_b  = (const float*)d_in[7];
    const float* pw1_w = (const float*)d_in[8];
    const float* pw1_b = (const float*)d_in[9];
    const float* grn_g = (const float*)d_in[10];
    const float* grn_b = (const float*)d_in[11];
    const float* pw2_w = (const float*)d_in[12];
    const float* pw2_b = (const float*)d_in[13];
    float* out = (float*)d_out;

    char* ws = (char*)d_ws;
    float*          freqs = (float*)(ws + OFF_FREQS);
    unsigned short* x     = (unsigned short*)(ws + OFF_X);
    unsigned short* xln   = (unsigned short*)(ws + OFF_XLN);
    unsigned short* h     = (unsigned short*)(ws + OFF_H);
    unsigned short* w1t   = (unsigned short*)(ws + OFF_W1T);
    unsigned short* w2t   = (unsigned short*)(ws + OFF_W2T);
    unsigned short* w2s   = (unsigned short*)(ws + OFF_W2S);
    float*          gxp   = (float*)(ws + OFF_GXP);
    float*          nx    = (float*)(ws + OFF_NX);
    float*          bias2 = (float*)(ws + OFF_B2);
    int*            pos   = (int*)(ws + OFF_POS);
    int*            lens  = (int*)(ws + OFF_LENS);

    freqs_kernel<<<LL, 256, 0, stream>>>(freqs);
    wtrans_kernel<<<dim3(HH / 64, DD / 64, NL), 256, 0, stream>>>(pw1_w, w1t, DD, HH);
    wtrans_kernel<<<dim3(DD / 64, HH / 64, NL), 256, 0, stream>>>(pw2_w, w2t, HH, DD);
    bias2_kernel<<<NL, 256, 0, stream>>>(pw2_b, grn_b, w2t, bias2);
    embed_kernel<<<MM, 64, 0, stream>>>(text, table, freqs, x);

    for (int layer = 0; layer < NL; layer++) {
        conv_ln_kernel<<<MM / (4 * CCH), 256, 0, stream>>>(x,
            dw_w + (size_t)layer * DD * 7, dw_b + (size_t)layer * DD,
            ln_g + (size_t)layer * DD, ln_b + (size_t)layer * DD, xln);

        gemm_bf16_kernel<DD, HH, 0><<<dim3(HH / 256, MM / 256), 512, 0, stream>>>(
            xln, w1t + (size_t)layer * HH * DD, pw1_b + (size_t)layer * HH,
            h, nullptr, nullptr, gxp);

        grn_stats_kernel<<<BB, 256, 0, stream>>>(gxp, grn_g + (size_t)layer * HH, nx);

        w2scale_kernel<<<dim3(DD * HH / (256 * 8), BB), 256, 0, stream>>>(
            w2t + (size_t)layer * DD * HH, nx, w2s);

        gemm_bf16_kernel<HH, DD, 1><<<dim3(DD / 256, MM / 256), 512, 0, stream>>>(
            h, w2s, bias2 + (size_t)layer * DD,
            nullptr, x, text, gxp);
    }

    upscan_kernel<<<BB, 256, 0, stream>>>(text, audio, pos, lens);
    upgather_kernel<<<MM, 128, 0, stream>>>(x, pos, lens, out);
}

// Round 19
// 566.338 us; speedup vs baseline: 1.1568x; 1.0659x over previous
//
#include <hip/hip_runtime.h>
#include <hip/hip_bf16.h>

#define BB 16
#define LL 2048
#define DD 512
#define HH 1024
#define NL 4
#define MM (BB*LL)   // 32768

typedef __attribute__((ext_vector_type(8))) short bh8;
typedef __attribute__((ext_vector_type(4))) float f4;
typedef __attribute__((ext_vector_type(4))) unsigned short us4;

typedef __attribute__((address_space(3))) unsigned int lds_u32;
typedef __attribute__((address_space(1))) const unsigned int glob_u32;

__device__ __forceinline__ void gld_lds16(const void* g, void* l) {
    __builtin_amdgcn_global_load_lds((glob_u32*)g, (lds_u32*)l, 16, 0, 0);
}

__device__ __forceinline__ unsigned short f2bf(float f) {
    unsigned int u = __float_as_uint(f);
    unsigned int r = (u + 0x7FFFu + ((u >> 16) & 1u)) >> 16;
    return (unsigned short)r;
}
__device__ __forceinline__ float bf2f(unsigned short u) {
    return __uint_as_float(((unsigned int)u) << 16);
}

// fast GELU (tanh form, abs err ~1e-4)
__device__ __forceinline__ float gelu_f(float v) {
    float y = 0.7978845608028654f * v * fmaf(0.044715f, v * v, 1.0f);
    float e = __expf(2.0f * y);
    float th = 1.0f - 2.0f * __builtin_amdgcn_rcpf(e + 1.0f);
    return 0.5f * v * (1.0f + th);
}

// ---------------- FREQS_CIS table [L, D]
__global__ __launch_bounds__(256) void freqs_kernel(float* __restrict__ fr) {
    int idx = blockIdx.x * 256 + threadIdx.x;
    int l = idx >> 8;
    int j = idx & 255;
    float f = exp2f(-(float)j * 0.051905126482615036f);  // log2(10000)/256
    float a = (float)l * f;
    fr[(size_t)l * DD + j]       = cosf(a);
    fr[(size_t)l * DD + 256 + j] = sinf(a);
}

// ---------------- weight transpose+convert: [NL][R][C] f32 -> [NL][C][R] bf16
__global__ __launch_bounds__(256) void wtrans_kernel(const float* __restrict__ w,
                                                     unsigned short* __restrict__ wt,
                                                     int R, int C) {
    __shared__ float ls[64][65];
    int layer = blockIdx.z;
    int tr = blockIdx.y;
    int tc = blockIdx.x;
    const float* src = w + (size_t)layer * R * C + (size_t)(tr * 64) * C + tc * 64;
    int t = threadIdx.x;
    #pragma unroll
    for (int s = 0; s < 4; s++) {
        int r = (t >> 4) + 16 * s, c = (t & 15) * 4;
        f4 v = *(const f4*)(src + (size_t)r * C + c);
        ls[r][c] = v.x; ls[r][c + 1] = v.y; ls[r][c + 2] = v.z; ls[r][c + 3] = v.w;
    }
    __syncthreads();
    unsigned short* dst = wt + (size_t)layer * R * C + (size_t)(tc * 64) * R + tr * 64;
    #pragma unroll
    for (int s = 0; s < 2; s++) {
        int idx = t + 256 * s;
        int c = idx >> 3;
        int r8 = (idx & 7) * 8;
        bh8 o;
        #pragma unroll
        for (int e = 0; e < 8; e++) o[e] = (short)f2bf(ls[r8 + e][c]);
        *(bh8*)(dst + (size_t)c * R + r8) = o;
    }
}

// ---------------- bias2[n] = pw2_b[n] + sum_k grn_b[k] * W2[k][n]
// Parallelized: grid (DD/8, NL), 512 threads; each wave owns one n, 64 lanes x 16 k.
__global__ __launch_bounds__(512) void bias2_kernel(const float* __restrict__ pw2_b,
                                                    const float* __restrict__ grn_b,
                                                    const unsigned short* __restrict__ w2t,
                                                    float* __restrict__ bias2) {
    int layer = blockIdx.y;
    int n = blockIdx.x * 8 + (threadIdx.x >> 6);
    int lane = threadIdx.x & 63;
    const unsigned short* wp = w2t + (size_t)layer * DD * HH + (size_t)n * HH + lane * 16;
    const float* gbp = grn_b + (size_t)layer * HH + lane * 16;
    float s = 0.f;
    #pragma unroll
    for (int q = 0; q < 2; q++) {
        bh8 wv = *(const bh8*)(wp + q * 8);
        #pragma unroll
        for (int e = 0; e < 8; e++) s = fmaf(gbp[q * 8 + e], bf2f((unsigned short)wv[e]), s);
    }
    #pragma unroll
    for (int off = 1; off <= 32; off <<= 1) s += __shfl_xor(s, off, 64);
    if (lane == 0) bias2[(size_t)layer * DD + n] = pw2_b[(size_t)layer * DD + n] + s;
}

// ---------------- embedding + freqs + mask -> bf16 x
__global__ __launch_bounds__(64) void embed_kernel(const int* __restrict__ text,
                                                   const float* __restrict__ table,
                                                   const float* __restrict__ fr,
                                                   unsigned short* __restrict__ x) {
    int bid = blockIdx.x;            // b*L + l
    int t = threadIdx.x;             // 64 lanes, 8 ch each
    int l = bid & (LL - 1);
    int d0 = t * 8;
    int tok = text[bid] + 1;
    bh8 o;
    if (tok != 0) {
        const float* e = table + (size_t)tok * DD + d0;
        const float* f = fr + (size_t)l * DD + d0;
        #pragma unroll
        for (int k = 0; k < 8; k++) o[k] = (short)f2bf(e[k] + f[k]);
    } else {
        #pragma unroll
        for (int k = 0; k < 8; k++) o[k] = 0;
    }
    *(bh8*)(x + (size_t)bid * DD + d0) = o;
}

// ---------------- depthwise conv7 + bias + LayerNorm -> bf16 (x input is bf16)
#define CCH 16
__global__ __launch_bounds__(256) void conv_ln_kernel(const unsigned short* __restrict__ x,
                                                      const float* __restrict__ dw_w,
                                                      const float* __restrict__ dw_b,
                                                      const float* __restrict__ ln_g,
                                                      const float* __restrict__ ln_b,
                                                      unsigned short* __restrict__ xln) {
    const int t = threadIdx.x;
    const int lane = t & 63, wv = t >> 6;
    const int chunk = blockIdx.x * 4 + wv;
    const int row0 = chunk * CCH;
    const int l0 = row0 & (LL - 1);
    const int d0 = lane * 8;
    const unsigned short* xb = x + ((size_t)(row0 >> 11) * LL) * DD + d0;

    float w[7][8], cb[8], g[8], be[8];
    #pragma unroll
    for (int e = 0; e < 8; e++) {
        #pragma unroll
        for (int k = 0; k < 7; k++) w[k][e] = dw_w[(d0 + e) * 7 + k];
        cb[e] = dw_b[d0 + e];
        g[e]  = ln_g[d0 + e];
        be[e] = ln_b[d0 + e];
    }

    float ring[8][8];
    #pragma unroll
    for (int ii = 0; ii < 8; ii++) {
        int i = ii - 3;
        int s = i & 7;
        int l = l0 + i;
        bool ok = (unsigned)l < LL;
        if (ok) {
            bh8 v = *(const bh8*)(xb + (size_t)l * DD);
            #pragma unroll
            for (int e = 0; e < 8; e++) ring[s][e] = bf2f((unsigned short)v[e]);
        } else {
            #pragma unroll
            for (int e = 0; e < 8; e++) ring[s][e] = 0.f;
        }
    }

    #pragma unroll
    for (int r = 0; r < CCH; r++) {
        float acc[8];
        #pragma unroll
        for (int e = 0; e < 8; e++) acc[e] = cb[e];
        #pragma unroll
        for (int k = 0; k < 7; k++) {
            int s = (r + k - 3) & 7;
            #pragma unroll
            for (int e = 0; e < 8; e++) acc[e] = fmaf(w[k][e], ring[s][e], acc[e]);
        }
        if (r + 5 <= CCH + 2) {
            int s = (r + 5) & 7;
            int l = l0 + r + 5;
            bool ok = (unsigned)l < LL;
            if (ok) {
                bh8 v = *(const bh8*)(xb + (size_t)l * DD);
                #pragma unroll
                for (int e = 0; e < 8; e++) ring[s][e] = bf2f((unsigned short)v[e]);
            } else {
                #pragma unroll
                for (int e = 0; e < 8; e++) ring[s][e] = 0.f;
            }
        }
        float s1 = 0.f, s2 = 0.f;
        #pragma unroll
        for (int e = 0; e < 8; e++) { s1 += acc[e]; s2 = fmaf(acc[e], acc[e], s2); }
        #pragma unroll
        for (int off = 1; off <= 32; off <<= 1) {
            s1 += __shfl_xor(s1, off, 64);
            s2 += __shfl_xor(s2, off, 64);
        }
        float mu = s1 * (1.0f / DD);
        float var = s2 * (1.0f / DD) - mu * mu;
        float rstd = rsqrtf(var + 1e-6f);
        bh8 o;
        #pragma unroll
        for (int e = 0; e < 8; e++) o[e] = (short)f2bf((acc[e] - mu) * rstd * g[e] + be[e]);
        *(bh8*)(xln + (size_t)(row0 + r) * DD + d0) = o;
    }
}

// ---------------- bf16 MFMA GEMM: 256x256 tile, 8 waves (2Mx4N), BK=64.
// Provably-correct 2-phase double-buffer (R9). XOR-swizzled LDS, XCD swizzle, setprio.
// MODE 0 (GEMM1): h = bf16(gelu(C+bias)); writes 64-row-block partials of sum(h^2) to aux
// MODE 1 (GEMM2): B is per-batch pre-scaled W2 (batch = m0>>11);
//   epilogue: stage C+bias as f32 in LDS (2 half-passes of 128 rows), then all 512
//   threads do coalesced us4 RMW on bf16 x: x = mask ? 0 : bf16(C + bias + f32(x)).
template<int KDIM, int NDIM, int MODE>
__global__ __launch_bounds__(512) void gemm_bf16_kernel(const unsigned short* __restrict__ A,
                                                        const unsigned short* __restrict__ Bt,
                                                        const float* __restrict__ bias,
                                                        unsigned short* __restrict__ hout,
                                                        unsigned short* __restrict__ xio,
                                                        const int* __restrict__ text,
                                                        float* __restrict__ aux) {
    __shared__ unsigned short lsbuf[65536];    // 128KB: A dbuf (0..32767), B dbuf (32768..65535)
    const int tid = threadIdx.x;
    constexpr int NX = NDIM / 256;
    constexpr int NWG = NX * (MM / 256);
    constexpr int NT = KDIM / 64;
    const int id = blockIdx.y * NX + blockIdx.x;
    const int sw = (id & 7) * (NWG / 8) + (id >> 3);     // XCD-chunked (NWG%8==0)
    const int m0 = (sw / NX) * 256;
    const int n0 = (sw % NX) * 256;

    const int lane = tid & 63, wid = tid >> 6;
    const int wm = wid >> 2, wn = wid & 3;               // wave tile: 128 rows x 64 cols
    const int ln = lane & 15;
    const int kq0 = ((lane >> 4) * 8) ^ ((lane & 7) << 3);
    const int kq1 = (32 + (lane >> 4) * 8) ^ ((lane & 7) << 3);
    const int arow = (wm * 128 + ln) * 64;               // + i*1024
    const int brow = (wn * 64 + ln) * 64;                // + j*1024

    const int srow = tid >> 3;
    const int scol = ((tid & 7) ^ (srow & 7)) << 3;      // inverse-swizzled global col (shorts)
    const int sdst = tid * 8;                            // LDS dest (shorts), +4096 for q=1
    const unsigned short* Asrc = A + ((size_t)m0 + srow) * KDIM + scol;
    const unsigned short* Bsrc;
    if constexpr (MODE == 0) Bsrc = Bt + ((size_t)n0 + srow) * KDIM + scol;
    else                     Bsrc = Bt + ((size_t)(m0 >> 11) * NDIM + n0 + srow) * KDIM + scol;

    f4 acc[8][4];
    #pragma unroll
    for (int i = 0; i < 8; i++)
        #pragma unroll
        for (int j = 0; j < 4; j++) acc[i][j] = (f4){0.f, 0.f, 0.f, 0.f};

#define LSA(bb) (lsbuf + (bb) * 16384)
#define LSB(bb) (lsbuf + 32768 + (bb) * 16384)
#define STG_ALL(bb, ko) do { _Pragma("unroll") for (int h = 0; h < 2; h++) {               \
    gld_lds16(Asrc + (size_t)(h * 128) * KDIM + (ko), LSA(bb) + h * 8192 + sdst);          \
    gld_lds16(Asrc + (size_t)(h * 128 + 64) * KDIM + (ko), LSA(bb) + h * 8192 + 4096 + sdst); \
    gld_lds16(Bsrc + (size_t)(h * 128) * KDIM + (ko), LSB(bb) + h * 8192 + sdst);          \
    gld_lds16(Bsrc + (size_t)(h * 128 + 64) * KDIM + (ko), LSB(bb) + h * 8192 + 4096 + sdst); } } while (0)
#define BOUNDARY do { asm volatile("s_waitcnt vmcnt(0)" ::: "memory");                     \
    __builtin_amdgcn_s_barrier(); __builtin_amdgcn_sched_barrier(0); } while (0)
#define RD_A03 do { _Pragma("unroll") for (int i = 0; i < 4; i++) {                        \
    aF[i][0] = *(bh8*)(LSA(cur) + arow + i * 1024 + kq0);                                  \
    aF[i][1] = *(bh8*)(LSA(cur) + arow + i * 1024 + kq1); } } while (0)
#define RD_A47 do { _Pragma("unroll") for (int i = 0; i < 4; i++) {                        \
    aF[i][0] = *(bh8*)(LSA(cur) + arow + (i + 4) * 1024 + kq0);                            \
    aF[i][1] = *(bh8*)(LSA(cur) + arow + (i + 4) * 1024 + kq1); } } while (0)
#define RD_B01 do { _Pragma("unroll") for (int j = 0; j < 2; j++) {                        \
    b0F[j][0] = *(bh8*)(LSB(cur) + brow + j * 1024 + kq0);                                 \
    b0F[j][1] = *(bh8*)(LSB(cur) + brow + j * 1024 + kq1); } } while (0)
#define RD_B23 do { _Pragma("unroll") for (int j = 0; j < 2; j++) {                        \
    b1F[j][0] = *(bh8*)(LSB(cur) + brow + (j + 2) * 1024 + kq0);                           \
    b1F[j][1] = *(bh8*)(LSB(cur) + brow + (j + 2) * 1024 + kq1); } } while (0)
#define MFMA_Q(i0, j0, bf) do { __builtin_amdgcn_s_setprio(1);                             \
    _Pragma("unroll") for (int i = 0; i < 4; i++)                                          \
    _Pragma("unroll") for (int j = 0; j < 2; j++) {                                        \
        acc[i + i0][j + j0] = __builtin_amdgcn_mfma_f32_16x16x32_bf16(aF[i][0], bf[j][0], acc[i + i0][j + j0], 0, 0, 0); \
        acc[i + i0][j + j0] = __builtin_amdgcn_mfma_f32_16x16x32_bf16(aF[i][1], bf[j][1], acc[i + i0][j + j0], 0, 0, 0); } \
    __builtin_amdgcn_s_setprio(0); } while (0)

    STG_ALL(0, 0);
    BOUNDARY;

    bh8 aF[4][2], b0F[2][2], b1F[2][2];
    for (int kt = 0; kt < NT; kt++) {
        const int cur = kt & 1, nb = cur ^ 1;
        const bool more = (kt + 1 < NT);
        if (more) { STG_ALL(nb, (kt + 1) * 64); }
        __builtin_amdgcn_sched_barrier(0);       // keep stage issues at top
        RD_A03; RD_B01;
        MFMA_Q(0, 0, b0F);
        RD_B23;
        MFMA_Q(0, 2, b1F);
        RD_A47;
        MFMA_Q(4, 2, b1F);
        MFMA_Q(4, 0, b0F);
        if (more) { BOUNDARY; }
    }
#undef STG_ALL
#undef BOUNDARY
#undef RD_A03
#undef RD_A47
#undef RD_B01
#undef RD_B23
#undef MFMA_Q
#undef LSA
#undef LSB

    const int rowOff = (lane >> 4) * 4;
    const int colOff = ln;
    if constexpr (MODE == 0) {
        float sj0[4] = {0.f, 0.f, 0.f, 0.f};
        float sj1[4] = {0.f, 0.f, 0.f, 0.f};
        #pragma unroll
        for (int i = 0; i < 8; i++) {
            #pragma unroll
            for (int j = 0; j < 4; j++) {
                int n = n0 + wn * 64 + j * 16 + colOff;
                float bn = bias[n];
                #pragma unroll
                for (int r = 0; r < 4; r++) {
                    int m = m0 + wm * 128 + i * 16 + rowOff + r;
                    float v = gelu_f(acc[i][j][r] + bn);
                    hout[(size_t)m * NDIM + n] = f2bf(v);
                    if (i < 4) sj0[j] = fmaf(v, v, sj0[j]);
                    else       sj1[j] = fmaf(v, v, sj1[j]);
                }
            }
        }
        #pragma unroll
        for (int j = 0; j < 4; j++) {
            sj0[j] += __shfl_xor(sj0[j], 16, 64);
            sj0[j] += __shfl_xor(sj0[j], 32, 64);
            sj1[j] += __shfl_xor(sj1[j], 16, 64);
            sj1[j] += __shfl_xor(sj1[j], 32, 64);
        }
        if (lane < 16) {
            int rb = (m0 + wm * 128) >> 6;       // 64-row blocks
            #pragma unroll
            for (int j = 0; j < 4; j++) {
                aux[(size_t)rb * HH + n0 + wn * 64 + j * 16 + lane] = sj0[j];
                aux[(size_t)(rb + 1) * HH + n0 + wn * 64 + j * 16 + lane] = sj1[j];
            }
        }
    } else {
        // staged coalesced RMW epilogue
        __syncthreads();                          // all waves done reading last K-tile
        float* cf = (float*)lsbuf;                // 128 x 256 f32 = 128KB
        #pragma unroll
        for (int half = 0; half < 2; half++) {
            if (wm == half) {
                #pragma unroll
                for (int i = 0; i < 8; i++)
                    #pragma unroll
                    for (int j = 0; j < 4; j++) {
                        int lc = wn * 64 + j * 16 + colOff;
                        float bn = bias[n0 + lc];
                        #pragma unroll
                        for (int r = 0; r < 4; r++) {
                            int lr = i * 16 + rowOff + r;
                            cf[lr * 256 + lc] = acc[i][j][r] + bn;
                        }
                    }
            }
            __syncthreads();
            #pragma unroll
            for (int k = 0; k < 16; k++) {
                int ci = tid + 512 * k;           // 8192 chunks of 4 cols
                int row = ci >> 6, ch = ci & 63;
                int m = m0 + half * 128 + row;
                size_t gb = (size_t)m * NDIM + n0 + ch * 4;
                bool msk = (text[m] == -1);
                us4 xo = *(const us4*)(xio + gb);
                f4 c = *(const f4*)&cf[row * 256 + ch * 4];
                us4 onew;
                onew.x = msk ? 0 : f2bf(c.x + bf2f(xo.x));
                onew.y = msk ? 0 : f2bf(c.y + bf2f(xo.y));
                onew.z = msk ? 0 : f2bf(c.z + bf2f(xo.z));
                onew.w = msk ? 0 : f2bf(c.w + bf2f(xo.w));
                *(us4*)(xio + gb) = onew;
            }
            __syncthreads();
        }
    }
}

// ---------------- GRN stats: scale[b][ch] = 1 + gg[ch] * Nx[b][ch]
__global__ __launch_bounds__(256) void grn_stats_kernel(const float* __restrict__ gxp,
                                                        const float* __restrict__ gg,
                                                        float* __restrict__ scale) {
    int b = blockIdx.x, t = threadIdx.x;
    float g[4];
    float s = 0.f;
    #pragma unroll
    for (int e = 0; e < 4; e++) {
        int ch = t + e * 256;
        float acc = 0.f;
        #pragma unroll
        for (int rb = 0; rb < 32; rb++) acc += gxp[(size_t)(b * 32 + rb) * HH + ch];
        g[e] = sqrtf(acc);
        s += g[e];
    }
    #pragma unroll
    for (int off = 32; off > 0; off >>= 1) s += __shfl_down(s, off);
    __shared__ float rs[4];
    if ((t & 63) == 0) rs[t >> 6] = s;
    __syncthreads();
    float tot = rs[0] + rs[1] + rs[2] + rs[3];
    float mean = tot * (1.0f / HH);
    float inv = 1.0f / (mean + 1e-6f);
    #pragma unroll
    for (int e = 0; e < 4; e++) {
        int ch = t + e * 256;
        scale[(size_t)b * HH + ch] = fmaf(gg[ch], g[e] * inv, 1.0f);
    }
}

// ---------------- per-batch scaled W2: w2s[b][n][k] = bf16(scale[b][k] * w2t[n][k])
__global__ __launch_bounds__(256) void w2scale_kernel(const unsigned short* __restrict__ w2t,
                                                      const float* __restrict__ scale,
                                                      unsigned short* __restrict__ w2s) {
    int b = blockIdx.y;
    size_t idx = ((size_t)blockIdx.x * 256 + threadIdx.x) * 8;   // over DD*HH
    int k = (int)(idx & (HH - 1));
    bh8 w = *(const bh8*)(w2t + idx);
    f4 s0 = *(const f4*)(scale + (size_t)b * HH + k);
    f4 s1 = *(const f4*)(scale + (size_t)b * HH + k + 4);
    float sv[8] = {s0.x,s0.y,s0.z,s0.w,s1.x,s1.y,s1.z,s1.w};
    bh8 o;
    #pragma unroll
    for (int e = 0; e < 8; e++) o[e] = (short)f2bf(bf2f((unsigned short)w[e]) * sv[e]);
    *(bh8*)(w2s + (size_t)b * DD * HH + idx) = o;
}

// ---------------- upsample scan (wave-ballot scan: 2 barriers/chunk)
__global__ __launch_bounds__(256) void upscan_kernel(const int* __restrict__ text,
                                                     const int* __restrict__ audio,
                                                     int* __restrict__ pos,
                                                     int* __restrict__ lens) {
    int b = blockIdx.x, t = threadIdx.x;
    int lane = t & 63, wv = t >> 6;
    __shared__ int wt[4], wa[4];
    int voff = 0, aoff = 0;
    for (int c = 0; c < LL / 256; c++) {
        int l = c * 256 + t;
        int am = audio[(size_t)b * LL + l];
        int tv = text[(size_t)b * LL + l];
        int valid = (am != 0 && tv != -1) ? 1 : 0;
        unsigned long long mv = __ballot(valid);
        unsigned long long ma = __ballot(am != 0);
        if (lane == 0) { wt[wv] = __popcll(mv); wa[wv] = __popcll(ma); }
        __syncthreads();
        int pre = 0;
        #pragma unroll
        for (int w = 0; w < 4; w++) if (w < wv) pre += wt[w];
        int incl = pre + (int)__popcll(mv << (63 - lane));   // bits 0..lane
        if (valid) pos[(size_t)b * LL + voff + incl - 1] = l;
        int bt = wt[0] + wt[1] + wt[2] + wt[3];
        int ba = wa[0] + wa[1] + wa[2] + wa[3];
        __syncthreads();
        voff += bt;
        aoff += ba;
    }
    if (t == 0) { lens[b * 2] = aoff; lens[b * 2 + 1] = voff; }
    for (int i = voff + t; i < LL; i += 256) pos[(size_t)b * LL + i] = LL - 1;
}

// ---------------- upsample gather (x bf16 -> out f32; 128 threads x 4 elems)
__global__ __launch_bounds__(128) void upgather_kernel(const unsigned short* __restrict__ x,
                                                       const int* __restrict__ pos,
                                                       const int* __restrict__ lens,
                                                       float* __restrict__ out) {
    int bid = blockIdx.x;
    int b = bid >> 11;
    int p = bid & (LL - 1);
    int t = threadIdx.x;
    int alen = lens[b * 2], vlen = lens[b * 2 + 1];
    f4 v = {0.f, 0.f, 0.f, 0.f};
    if (p < alen && vlen > 0) {
        int vl = vlen < 1 ? 1 : vlen;
        int base = alen / vl, rem = alen % vl;
        int cut = (vl - rem) * base;
        int j;
        if (p < cut) j = p / (base < 1 ? 1 : base);
        else j = (vl - rem) + (p - cut) / (base + 1);
        j = j < 0 ? 0 : (j > LL - 1 ? LL - 1 : j);
        int s = pos[(size_t)b * LL + j];
        s = s < 0 ? 0 : (s > LL - 1 ? LL - 1 : s);
        us4 u = *(const us4*)(x + ((size_t)b * LL + s) * DD + t * 4);
        v.x = bf2f(u.x); v.y = bf2f(u.y); v.z = bf2f(u.z); v.w = bf2f(u.w);
    }
    *(f4*)(out + (size_t)bid * DD + t * 4) = v;
}

// ---------------- workspace layout (bytes)
#define OFF_FREQS  ((size_t)0)
#define OFF_X      (OFF_FREQS + (size_t)LL * DD * 4)          // 4 MB (freqs f32)
#define OFF_XLN    (OFF_X + (size_t)MM * DD * 2)              // +32 MB (x bf16)
#define OFF_H      (OFF_XLN + (size_t)MM * DD * 2)            // +32 MB
#define OFF_W1T    (OFF_H + (size_t)MM * HH * 2)              // +64 MB
#define OFF_W2T    (OFF_W1T + (size_t)NL * HH * DD * 2)       // +4 MB
#define OFF_GXP    (OFF_W2T + (size_t)NL * DD * HH * 2)       // +4 MB
#define OFF_NX     (OFF_GXP + (size_t)512 * HH * 4)           // +2 MB
#define OFF_B2     (OFF_NX + (size_t)BB * HH * 4)             // +64 KB
#define OFF_POS    (OFF_B2 + (size_t)NL * DD * 4)             // +8 KB
#define OFF_LENS   (OFF_POS + (size_t)BB * LL * 4)            // +128 KB
// w2s (16 MB) overlays xln's region (xln dead between GEMM1(layer) and conv_ln(layer+1))
#define OFF_W2S    OFF_XLN

extern "C" void kernel_launch(void* const* d_in, const int* in_sizes, int n_in,
                              void* d_out, int out_size, void* d_ws, size_t ws_size,
                              hipStream_t stream) {
    const int*   text  = (const int*)d_in[0];
    const int*   audio = (const int*)d_in[1];
    const float* table = (const float*)d_in[3];
    const float* dw_w  = (const float*)d_in[4];
    const float* dw_b  = (const float*)d_in[5];
    const float* ln_g  = (const float*)d_in[6];
    const float* ln_b  = (const float*)d_in[7];
    const float* pw1_w = (const float*)d_in[8];
    const float* pw1_b = (const float*)d_in[9];
    const float* grn_g = (const float*)d_in[10];
    const float* grn_b = (const float*)d_in[11];
    const float* pw2_w = (const float*)d_in[12];
    const float* pw2_b = (const float*)d_in[13];
    float* out = (float*)d_out;

    char* ws = (char*)d_ws;
    float*          freqs = (float*)(ws + OFF_FREQS);
    unsigned short* x     = (unsigned short*)(ws + OFF_X);
    unsigned short* xln   = (unsigned short*)(ws + OFF_XLN);
    unsigned short* h     = (unsigned short*)(ws + OFF_H);
    unsigned short* w1t   = (unsigned short*)(ws + OFF_W1T);
    unsigned short* w2t   = (unsigned short*)(ws + OFF_W2T);
    unsigned short* w2s   = (unsigned short*)(ws + OFF_W2S);
    float*          gxp   = (float*)(ws + OFF_GXP);
    float*          nx    = (float*)(ws + OFF_NX);
    float*          bias2 = (float*)(ws + OFF_B2);
    int*            pos   = (int*)(ws + OFF_POS);
    int*            lens  = (int*)(ws + OFF_LENS);

    freqs_kernel<<<LL, 256, 0, stream>>>(freqs);
    wtrans_kernel<<<dim3(HH / 64, DD / 64, NL), 256, 0, stream>>>(pw1_w, w1t, DD, HH);
    wtrans_kernel<<<dim3(DD / 64, HH / 64, NL), 256, 0, stream>>>(pw2_w, w2t, HH, DD);
    bias2_kernel<<<dim3(DD / 8, NL), 512, 0, stream>>>(pw2_b, grn_b, w2t, bias2);
    embed_kernel<<<MM, 64, 0, stream>>>(text, table, freqs, x);

    for (int layer = 0; layer < NL; layer++) {
        conv_ln_kernel<<<MM / (4 * CCH), 256, 0, stream>>>(x,
            dw_w + (size_t)layer * DD * 7, dw_b + (size_t)layer * DD,
            ln_g + (size_t)layer * DD, ln_b + (size_t)layer * DD, xln);

        gemm_bf16_kernel<DD, HH, 0><<<dim3(HH / 256, MM / 256), 512, 0, stream>>>(
            xln, w1t + (size_t)layer * HH * DD, pw1_b + (size_t)layer * HH,
            h, nullptr, nullptr, gxp);

        grn_stats_kernel<<<BB, 256, 0, stream>>>(gxp, grn_g + (size_t)layer * HH, nx);

        w2scale_kernel<<<dim3(DD * HH / (256 * 8), BB), 256, 0, stream>>>(
            w2t + (size_t)layer * DD * HH, nx, w2s);

        gemm_bf16_kernel<HH, DD, 1><<<dim3(DD / 256, MM / 256), 512, 0, stream>>>(
            h, w2s, bias2 + (size_t)layer * DD,
            nullptr, x, text, gxp);
    }

    upscan_kernel<<<BB, 256, 0, stream>>>(text, audio, pos, lens);
    upgather_kernel<<<MM, 128, 0, stream>>>(x, pos, lens, out);
}

// Round 20
// 529.193 us; speedup vs baseline: 1.2380x; 1.0702x over previous
//
#include <hip/hip_runtime.h>
#include <hip/hip_bf16.h>

#define BB 16
#define LL 2048
#define DD 512
#define HH 1024
#define NL 4
#define MM (BB*LL)   // 32768

typedef __attribute__((ext_vector_type(8))) short bh8;
typedef __attribute__((ext_vector_type(4))) float f4;
typedef __attribute__((ext_vector_type(4))) unsigned short us4;

typedef __attribute__((address_space(3))) unsigned int lds_u32;
typedef __attribute__((address_space(1))) const unsigned int glob_u32;

__device__ __forceinline__ void gld_lds16(const void* g, void* l) {
    __builtin_amdgcn_global_load_lds((glob_u32*)g, (lds_u32*)l, 16, 0, 0);
}

__device__ __forceinline__ unsigned short f2bf(float f) {
    unsigned int u = __float_as_uint(f);
    unsigned int r = (u + 0x7FFFu + ((u >> 16) & 1u)) >> 16;
    return (unsigned short)r;
}
__device__ __forceinline__ float bf2f(unsigned short u) {
    return __uint_as_float(((unsigned int)u) << 16);
}

// fast GELU (tanh form, abs err ~1e-4)
__device__ __forceinline__ float gelu_f(float v) {
    float y = 0.7978845608028654f * v * fmaf(0.044715f, v * v, 1.0f);
    float e = __expf(2.0f * y);
    float th = 1.0f - 2.0f * __builtin_amdgcn_rcpf(e + 1.0f);
    return 0.5f * v * (1.0f + th);
}

// ---------------- FREQS_CIS table [L, D]
__global__ __launch_bounds__(256) void freqs_kernel(float* __restrict__ fr) {
    int idx = blockIdx.x * 256 + threadIdx.x;
    int l = idx >> 8;
    int j = idx & 255;
    float f = exp2f(-(float)j * 0.051905126482615036f);  // log2(10000)/256
    float a = (float)l * f;
    fr[(size_t)l * DD + j]       = cosf(a);
    fr[(size_t)l * DD + 256 + j] = sinf(a);
}

// ---------------- weight transpose+convert: [NL][R][C] f32 -> [NL][C][R] bf16
__global__ __launch_bounds__(256) void wtrans_kernel(const float* __restrict__ w,
                                                     unsigned short* __restrict__ wt,
                                                     int R, int C) {
    __shared__ float ls[64][65];
    int layer = blockIdx.z;
    int tr = blockIdx.y;
    int tc = blockIdx.x;
    const float* src = w + (size_t)layer * R * C + (size_t)(tr * 64) * C + tc * 64;
    int t = threadIdx.x;
    #pragma unroll
    for (int s = 0; s < 4; s++) {
        int r = (t >> 4) + 16 * s, c = (t & 15) * 4;
        f4 v = *(const f4*)(src + (size_t)r * C + c);
        ls[r][c] = v.x; ls[r][c + 1] = v.y; ls[r][c + 2] = v.z; ls[r][c + 3] = v.w;
    }
    __syncthreads();
    unsigned short* dst = wt + (size_t)layer * R * C + (size_t)(tc * 64) * R + tr * 64;
    #pragma unroll
    for (int s = 0; s < 2; s++) {
        int idx = t + 256 * s;
        int c = idx >> 3;
        int r8 = (idx & 7) * 8;
        bh8 o;
        #pragma unroll
        for (int e = 0; e < 8; e++) o[e] = (short)f2bf(ls[r8 + e][c]);
        *(bh8*)(dst + (size_t)c * R + r8) = o;
    }
}

// ---------------- bias2[n] = pw2_b[n] + sum_k grn_b[k] * W2[k][n]
// Parallelized: grid (DD/8, NL), 512 threads; each wave owns one n, 64 lanes x 16 k.
__global__ __launch_bounds__(512) void bias2_kernel(const float* __restrict__ pw2_b,
                                                    const float* __restrict__ grn_b,
                                                    const unsigned short* __restrict__ w2t,
                                                    float* __restrict__ bias2) {
    int layer = blockIdx.y;
    int n = blockIdx.x * 8 + (threadIdx.x >> 6);
    int lane = threadIdx.x & 63;
    const unsigned short* wp = w2t + (size_t)layer * DD * HH + (size_t)n * HH + lane * 16;
    const float* gbp = grn_b + (size_t)layer * HH + lane * 16;
    float s = 0.f;
    #pragma unroll
    for (int q = 0; q < 2; q++) {
        bh8 wv = *(const bh8*)(wp + q * 8);
        #pragma unroll
        for (int e = 0; e < 8; e++) s = fmaf(gbp[q * 8 + e], bf2f((unsigned short)wv[e]), s);
    }
    #pragma unroll
    for (int off = 1; off <= 32; off <<= 1) s += __shfl_xor(s, off, 64);
    if (lane == 0) bias2[(size_t)layer * DD + n] = pw2_b[(size_t)layer * DD + n] + s;
}

// ---------------- embedding + freqs + mask -> bf16 x
__global__ __launch_bounds__(64) void embed_kernel(const int* __restrict__ text,
                                                   const float* __restrict__ table,
                                                   const float* __restrict__ fr,
                                                   unsigned short* __restrict__ x) {
    int bid = blockIdx.x;            // b*L + l
    int t = threadIdx.x;             // 64 lanes, 8 ch each
    int l = bid & (LL - 1);
    int d0 = t * 8;
    int tok = text[bid] + 1;
    bh8 o;
    if (tok != 0) {
        const float* e = table + (size_t)tok * DD + d0;
        const float* f = fr + (size_t)l * DD + d0;
        #pragma unroll
        for (int k = 0; k < 8; k++) o[k] = (short)f2bf(e[k] + f[k]);
    } else {
        #pragma unroll
        for (int k = 0; k < 8; k++) o[k] = 0;
    }
    *(bh8*)(x + (size_t)bid * DD + d0) = o;
}

// ---------------- depthwise conv7 + bias + LayerNorm -> bf16 (x input is bf16)
#define CCH 16
__global__ __launch_bounds__(256) void conv_ln_kernel(const unsigned short* __restrict__ x,
                                                      const float* __restrict__ dw_w,
                                                      const float* __restrict__ dw_b,
                                                      const float* __restrict__ ln_g,
                                                      const float* __restrict__ ln_b,
                                                      unsigned short* __restrict__ xln) {
    const int t = threadIdx.x;
    const int lane = t & 63, wv = t >> 6;
    const int chunk = blockIdx.x * 4 + wv;
    const int row0 = chunk * CCH;
    const int l0 = row0 & (LL - 1);
    const int d0 = lane * 8;
    const unsigned short* xb = x + ((size_t)(row0 >> 11) * LL) * DD + d0;

    float w[7][8], cb[8], g[8], be[8];
    #pragma unroll
    for (int e = 0; e < 8; e++) {
        #pragma unroll
        for (int k = 0; k < 7; k++) w[k][e] = dw_w[(d0 + e) * 7 + k];
        cb[e] = dw_b[d0 + e];
        g[e]  = ln_g[d0 + e];
        be[e] = ln_b[d0 + e];
    }

    float ring[8][8];
    #pragma unroll
    for (int ii = 0; ii < 8; ii++) {
        int i = ii - 3;
        int s = i & 7;
        int l = l0 + i;
        bool ok = (unsigned)l < LL;
        if (ok) {
            bh8 v = *(const bh8*)(xb + (size_t)l * DD);
            #pragma unroll
            for (int e = 0; e < 8; e++) ring[s][e] = bf2f((unsigned short)v[e]);
        } else {
            #pragma unroll
            for (int e = 0; e < 8; e++) ring[s][e] = 0.f;
        }
    }

    #pragma unroll
    for (int r = 0; r < CCH; r++) {
        float acc[8];
        #pragma unroll
        for (int e = 0; e < 8; e++) acc[e] = cb[e];
        #pragma unroll
        for (int k = 0; k < 7; k++) {
            int s = (r + k - 3) & 7;
            #pragma unroll
            for (int e = 0; e < 8; e++) acc[e] = fmaf(w[k][e], ring[s][e], acc[e]);
        }
        if (r + 5 <= CCH + 2) {
            int s = (r + 5) & 7;
            int l = l0 + r + 5;
            bool ok = (unsigned)l < LL;
            if (ok) {
                bh8 v = *(const bh8*)(xb + (size_t)l * DD);
                #pragma unroll
                for (int e = 0; e < 8; e++) ring[s][e] = bf2f((unsigned short)v[e]);
            } else {
                #pragma unroll
                for (int e = 0; e < 8; e++) ring[s][e] = 0.f;
            }
        }
        float s1 = 0.f, s2 = 0.f;
        #pragma unroll
        for (int e = 0; e < 8; e++) { s1 += acc[e]; s2 = fmaf(acc[e], acc[e], s2); }
        #pragma unroll
        for (int off = 1; off <= 32; off <<= 1) {
            s1 += __shfl_xor(s1, off, 64);
            s2 += __shfl_xor(s2, off, 64);
        }
        float mu = s1 * (1.0f / DD);
        float var = s2 * (1.0f / DD) - mu * mu;
        float rstd = rsqrtf(var + 1e-6f);
        bh8 o;
        #pragma unroll
        for (int e = 0; e < 8; e++) o[e] = (short)f2bf((acc[e] - mu) * rstd * g[e] + be[e]);
        *(bh8*)(xln + (size_t)(row0 + r) * DD + d0) = o;
    }
}

// ---------------- bf16 MFMA GEMM: 256x256 tile, 8 waves (2Mx4N), BK=64.
// Provably-correct 2-phase double-buffer (R9). XOR-swizzled LDS, XCD swizzle, setprio.
// MODE 0 (GEMM1): h = bf16(gelu(C+bias)); writes 64-row-block partials of sum(h^2) to aux
// MODE 1 (GEMM2): B is per-batch pre-scaled W2 (batch = m0>>11);
//   epilogue: stage C+bias as f32 in LDS (2 half-passes of 128 rows), then all 512
//   threads do coalesced us4 RMW on bf16 x: x = mask ? 0 : bf16(C + bias + f32(x)).
template<int KDIM, int NDIM, int MODE>
__global__ __launch_bounds__(512) void gemm_bf16_kernel(const unsigned short* __restrict__ A,
                                                        const unsigned short* __restrict__ Bt,
                                                        const float* __restrict__ bias,
                                                        unsigned short* __restrict__ hout,
                                                        unsigned short* __restrict__ xio,
                                                        const int* __restrict__ text,
                                                        float* __restrict__ aux) {
    __shared__ unsigned short lsbuf[65536];    // 128KB: A dbuf (0..32767), B dbuf (32768..65535)
    const int tid = threadIdx.x;
    constexpr int NX = NDIM / 256;
    constexpr int NWG = NX * (MM / 256);
    constexpr int NT = KDIM / 64;
    const int id = blockIdx.y * NX + blockIdx.x;
    const int sw = (id & 7) * (NWG / 8) + (id >> 3);     // XCD-chunked (NWG%8==0)
    const int m0 = (sw / NX) * 256;
    const int n0 = (sw % NX) * 256;

    const int lane = tid & 63, wid = tid >> 6;
    const int wm = wid >> 2, wn = wid & 3;               // wave tile: 128 rows x 64 cols
    const int ln = lane & 15;
    const int kq0 = ((lane >> 4) * 8) ^ ((lane & 7) << 3);
    const int kq1 = (32 + (lane >> 4) * 8) ^ ((lane & 7) << 3);
    const int arow = (wm * 128 + ln) * 64;               // + i*1024
    const int brow = (wn * 64 + ln) * 64;                // + j*1024

    const int srow = tid >> 3;
    const int scol = ((tid & 7) ^ (srow & 7)) << 3;      // inverse-swizzled global col (shorts)
    const int sdst = tid * 8;                            // LDS dest (shorts), +4096 for q=1
    const unsigned short* Asrc = A + ((size_t)m0 + srow) * KDIM + scol;
    const unsigned short* Bsrc;
    if constexpr (MODE == 0) Bsrc = Bt + ((size_t)n0 + srow) * KDIM + scol;
    else                     Bsrc = Bt + ((size_t)(m0 >> 11) * NDIM + n0 + srow) * KDIM + scol;

    f4 acc[8][4];
    #pragma unroll
    for (int i = 0; i < 8; i++)
        #pragma unroll
        for (int j = 0; j < 4; j++) acc[i][j] = (f4){0.f, 0.f, 0.f, 0.f};

#define LSA(bb) (lsbuf + (bb) * 16384)
#define LSB(bb) (lsbuf + 32768 + (bb) * 16384)
#define STG_ALL(bb, ko) do { _Pragma("unroll") for (int h = 0; h < 2; h++) {               \
    gld_lds16(Asrc + (size_t)(h * 128) * KDIM + (ko), LSA(bb) + h * 8192 + sdst);          \
    gld_lds16(Asrc + (size_t)(h * 128 + 64) * KDIM + (ko), LSA(bb) + h * 8192 + 4096 + sdst); \
    gld_lds16(Bsrc + (size_t)(h * 128) * KDIM + (ko), LSB(bb) + h * 8192 + sdst);          \
    gld_lds16(Bsrc + (size_t)(h * 128 + 64) * KDIM + (ko), LSB(bb) + h * 8192 + 4096 + sdst); } } while (0)
#define BOUNDARY do { asm volatile("s_waitcnt vmcnt(0)" ::: "memory");                     \
    __builtin_amdgcn_s_barrier(); __builtin_amdgcn_sched_barrier(0); } while (0)
#define RD_A03 do { _Pragma("unroll") for (int i = 0; i < 4; i++) {                        \
    aF[i][0] = *(bh8*)(LSA(cur) + arow + i * 1024 + kq0);                                  \
    aF[i][1] = *(bh8*)(LSA(cur) + arow + i * 1024 + kq1); } } while (0)
#define RD_A47 do { _Pragma("unroll") for (int i = 0; i < 4; i++) {                        \
    aF[i][0] = *(bh8*)(LSA(cur) + arow + (i + 4) * 1024 + kq0);                            \
    aF[i][1] = *(bh8*)(LSA(cur) + arow + (i + 4) * 1024 + kq1); } } while (0)
#define RD_B01 do { _Pragma("unroll") for (int j = 0; j < 2; j++) {                        \
    b0F[j][0] = *(bh8*)(LSB(cur) + brow + j * 1024 + kq0);                                 \
    b0F[j][1] = *(bh8*)(LSB(cur) + brow + j * 1024 + kq1); } } while (0)
#define RD_B23 do { _Pragma("unroll") for (int j = 0; j < 2; j++) {                        \
    b1F[j][0] = *(bh8*)(LSB(cur) + brow + (j + 2) * 1024 + kq0);                           \
    b1F[j][1] = *(bh8*)(LSB(cur) + brow + (j + 2) * 1024 + kq1); } } while (0)
#define MFMA_Q(i0, j0, bf) do { __builtin_amdgcn_s_setprio(1);                             \
    _Pragma("unroll") for (int i = 0; i < 4; i++)                                          \
    _Pragma("unroll") for (int j = 0; j < 2; j++) {                                        \
        acc[i + i0][j + j0] = __builtin_amdgcn_mfma_f32_16x16x32_bf16(aF[i][0], bf[j][0], acc[i + i0][j + j0], 0, 0, 0); \
        acc[i + i0][j + j0] = __builtin_amdgcn_mfma_f32_16x16x32_bf16(aF[i][1], bf[j][1], acc[i + i0][j + j0], 0, 0, 0); } \
    __builtin_amdgcn_s_setprio(0); } while (0)

    STG_ALL(0, 0);
    BOUNDARY;

    bh8 aF[4][2], b0F[2][2], b1F[2][2];
    for (int kt = 0; kt < NT; kt++) {
        const int cur = kt & 1, nb = cur ^ 1;
        const bool more = (kt + 1 < NT);
        if (more) { STG_ALL(nb, (kt + 1) * 64); }
        __builtin_amdgcn_sched_barrier(0);       // keep stage issues at top
        RD_A03; RD_B01;
        MFMA_Q(0, 0, b0F);
        RD_B23;
        MFMA_Q(0, 2, b1F);
        RD_A47;
        MFMA_Q(4, 2, b1F);
        MFMA_Q(4, 0, b0F);
        if (more) { BOUNDARY; }
    }
#undef STG_ALL
#undef BOUNDARY
#undef RD_A03
#undef RD_A47
#undef RD_B01
#undef RD_B23
#undef MFMA_Q
#undef LSA
#undef LSB

    const int rowOff = (lane >> 4) * 4;
    const int colOff = ln;
    if constexpr (MODE == 0) {
        float sj0[4] = {0.f, 0.f, 0.f, 0.f};
        float sj1[4] = {0.f, 0.f, 0.f, 0.f};
        #pragma unroll
        for (int i = 0; i < 8; i++) {
            #pragma unroll
            for (int j = 0; j < 4; j++) {
                int n = n0 + wn * 64 + j * 16 + colOff;
                float bn = bias[n];
                #pragma unroll
                for (int r = 0; r < 4; r++) {
                    int m = m0 + wm * 128 + i * 16 + rowOff + r;
                    float v = gelu_f(acc[i][j][r] + bn);
                    hout[(size_t)m * NDIM + n] = f2bf(v);
                    if (i < 4) sj0[j] = fmaf(v, v, sj0[j]);
                    else       sj1[j] = fmaf(v, v, sj1[j]);
                }
            }
        }
        #pragma unroll
        for (int j = 0; j < 4; j++) {
            sj0[j] += __shfl_xor(sj0[j], 16, 64);
            sj0[j] += __shfl_xor(sj0[j], 32, 64);
            sj1[j] += __shfl_xor(sj1[j], 16, 64);
            sj1[j] += __shfl_xor(sj1[j], 32, 64);
        }
        if (lane < 16) {
            int rb = (m0 + wm * 128) >> 6;       // 64-row blocks
            #pragma unroll
            for (int j = 0; j < 4; j++) {
                aux[(size_t)rb * HH + n0 + wn * 64 + j * 16 + lane] = sj0[j];
                aux[(size_t)(rb + 1) * HH + n0 + wn * 64 + j * 16 + lane] = sj1[j];
            }
        }
    } else {
        // staged coalesced RMW epilogue
        __syncthreads();                          // all waves done reading last K-tile
        float* cf = (float*)lsbuf;                // 128 x 256 f32 = 128KB
        #pragma unroll
        for (int half = 0; half < 2; half++) {
            if (wm == half) {
                #pragma unroll
                for (int i = 0; i < 8; i++)
                    #pragma unroll
                    for (int j = 0; j < 4; j++) {
                        int lc = wn * 64 + j * 16 + colOff;
                        float bn = bias[n0 + lc];
                        #pragma unroll
                        for (int r = 0; r < 4; r++) {
                            int lr = i * 16 + rowOff + r;
                            cf[lr * 256 + lc] = acc[i][j][r] + bn;
                        }
                    }
            }
            __syncthreads();
            #pragma unroll
            for (int k = 0; k < 16; k++) {
                int ci = tid + 512 * k;           // 8192 chunks of 4 cols
                int row = ci >> 6, ch = ci & 63;
                int m = m0 + half * 128 + row;
                size_t gb = (size_t)m * NDIM + n0 + ch * 4;
                bool msk = (text[m] == -1);
                us4 xo = *(const us4*)(xio + gb);
                f4 c = *(const f4*)&cf[row * 256 + ch * 4];
                us4 onew;
                onew.x = msk ? 0 : f2bf(c.x + bf2f(xo.x));
                onew.y = msk ? 0 : f2bf(c.y + bf2f(xo.y));
                onew.z = msk ? 0 : f2bf(c.z + bf2f(xo.z));
                onew.w = msk ? 0 : f2bf(c.w + bf2f(xo.w));
                *(us4*)(xio + gb) = onew;
            }
            __syncthreads();
        }
    }
}

// ---------------- GRN stats: scale[b][ch] = 1 + gg[ch] * Nx[b][ch]
// Widened: 16 blocks x 1024 threads (one thread per channel; 16 waves/block).
__global__ __launch_bounds__(1024) void grn_stats_kernel(const float* __restrict__ gxp,
                                                         const float* __restrict__ gg,
                                                         float* __restrict__ scale) {
    int b = blockIdx.x, ch = threadIdx.x;
    int lane = ch & 63, wv = ch >> 6;
    float acc = 0.f;
    #pragma unroll
    for (int rb = 0; rb < 32; rb++) acc += gxp[(size_t)(b * 32 + rb) * HH + ch];
    float g = sqrtf(acc);
    float s = g;
    #pragma unroll
    for (int off = 1; off <= 32; off <<= 1) s += __shfl_xor(s, off, 64);
    __shared__ float rs[16];
    if (lane == 0) rs[wv] = s;
    __syncthreads();
    float tot = 0.f;
    #pragma unroll
    for (int w = 0; w < 16; w++) tot += rs[w];
    float mean = tot * (1.0f / HH);
    float inv = 1.0f / (mean + 1e-6f);
    scale[(size_t)b * HH + ch] = fmaf(gg[ch], g * inv, 1.0f);
}

// ---------------- per-batch scaled W2: w2s[b][n][k] = bf16(scale[b][k] * w2t[n][k])
__global__ __launch_bounds__(256) void w2scale_kernel(const unsigned short* __restrict__ w2t,
                                                      const float* __restrict__ scale,
                                                      unsigned short* __restrict__ w2s) {
    int b = blockIdx.y;
    size_t idx = ((size_t)blockIdx.x * 256 + threadIdx.x) * 8;   // over DD*HH
    int k = (int)(idx & (HH - 1));
    bh8 w = *(const bh8*)(w2t + idx);
    f4 s0 = *(const f4*)(scale + (size_t)b * HH + k);
    f4 s1 = *(const f4*)(scale + (size_t)b * HH + k + 4);
    float sv[8] = {s0.x,s0.y,s0.z,s0.w,s1.x,s1.y,s1.z,s1.w};
    bh8 o;
    #pragma unroll
    for (int e = 0; e < 8; e++) o[e] = (short)f2bf(bf2f((unsigned short)w[e]) * sv[e]);
    *(bh8*)(w2s + (size_t)b * DD * HH + idx) = o;
}

// ---------------- upsample scan (wave-ballot scan: 2 barriers/chunk)
__global__ __launch_bounds__(256) void upscan_kernel(const int* __restrict__ text,
                                                     const int* __restrict__ audio,
                                                     int* __restrict__ pos,
                                                     int* __restrict__ lens) {
    int b = blockIdx.x, t = threadIdx.x;
    int lane = t & 63, wv = t >> 6;
    __shared__ int wt[4], wa[4];
    int voff = 0, aoff = 0;
    for (int c = 0; c < LL / 256; c++) {
        int l = c * 256 + t;
        int am = audio[(size_t)b * LL + l];
        int tv = text[(size_t)b * LL + l];
        int valid = (am != 0 && tv != -1) ? 1 : 0;
        unsigned long long mv = __ballot(valid);
        unsigned long long ma = __ballot(am != 0);
        if (lane == 0) { wt[wv] = __popcll(mv); wa[wv] = __popcll(ma); }
        __syncthreads();
        int pre = 0;
        #pragma unroll
        for (int w = 0; w < 4; w++) if (w < wv) pre += wt[w];
        int incl = pre + (int)__popcll(mv << (63 - lane));   // bits 0..lane
        if (valid) pos[(size_t)b * LL + voff + incl - 1] = l;
        int bt = wt[0] + wt[1] + wt[2] + wt[3];
        int ba = wa[0] + wa[1] + wa[2] + wa[3];
        __syncthreads();
        voff += bt;
        aoff += ba;
    }
    if (t == 0) { lens[b * 2] = aoff; lens[b * 2 + 1] = voff; }
    for (int i = voff + t; i < LL; i += 256) pos[(size_t)b * LL + i] = LL - 1;
}

// ---------------- upsample gather (x bf16 -> out f32; 128 threads x 4 elems)
__global__ __launch_bounds__(128) void upgather_kernel(const unsigned short* __restrict__ x,
                                                       const int* __restrict__ pos,
                                                       const int* __restrict__ lens,
                                                       float* __restrict__ out) {
    int bid = blockIdx.x;
    int b = bid >> 11;
    int p = bid & (LL - 1);
    int t = threadIdx.x;
    int alen = lens[b * 2], vlen = lens[b * 2 + 1];
    f4 v = {0.f, 0.f, 0.f, 0.f};
    if (p < alen && vlen > 0) {
        int vl = vlen < 1 ? 1 : vlen;
        int base = alen / vl, rem = alen % vl;
        int cut = (vl - rem) * base;
        int j;
        if (p < cut) j = p / (base < 1 ? 1 : base);
        else j = (vl - rem) + (p - cut) / (base + 1);
        j = j < 0 ? 0 : (j > LL - 1 ? LL - 1 : j);
        int s = pos[(size_t)b * LL + j];
        s = s < 0 ? 0 : (s > LL - 1 ? LL - 1 : s);
        us4 u = *(const us4*)(x + ((size_t)b * LL + s) * DD + t * 4);
        v.x = bf2f(u.x); v.y = bf2f(u.y); v.z = bf2f(u.z); v.w = bf2f(u.w);
    }
    *(f4*)(out + (size_t)bid * DD + t * 4) = v;
}

// ---------------- workspace layout (bytes)
#define OFF_FREQS  ((size_t)0)
#define OFF_X      (OFF_FREQS + (size_t)LL * DD * 4)          // 4 MB (freqs f32)
#define OFF_XLN    (OFF_X + (size_t)MM * DD * 2)              // +32 MB (x bf16)
#define OFF_H      (OFF_XLN + (size_t)MM * DD * 2)            // +32 MB
#define OFF_W1T    (OFF_H + (size_t)MM * HH * 2)              // +64 MB
#define OFF_W2T    (OFF_W1T + (size_t)NL * HH * DD * 2)       // +4 MB
#define OFF_GXP    (OFF_W2T + (size_t)NL * DD * HH * 2)       // +4 MB
#define OFF_NX     (OFF_GXP + (size_t)512 * HH * 4)           // +2 MB
#define OFF_B2     (OFF_NX + (size_t)BB * HH * 4)             // +64 KB
#define OFF_POS    (OFF_B2 + (size_t)NL * DD * 4)             // +8 KB
#define OFF_LENS   (OFF_POS + (size_t)BB * LL * 4)            // +128 KB
// w2s (16 MB) overlays xln's region (xln dead between GEMM1(layer) and conv_ln(layer+1))
#define OFF_W2S    OFF_XLN

extern "C" void kernel_launch(void* const* d_in, const int* in_sizes, int n_in,
                              void* d_out, int out_size, void* d_ws, size_t ws_size,
                              hipStream_t stream) {
    const int*   text  = (const int*)d_in[0];
    const int*   audio = (const int*)d_in[1];
    const float* table = (const float*)d_in[3];
    const float* dw_w  = (const float*)d_in[4];
    const float* dw_b  = (const float*)d_in[5];
    const float* ln_g  = (const float*)d_in[6];
    const float* ln_b  = (const float*)d_in[7];
    const float* pw1_w = (const float*)d_in[8];
    const float* pw1_b = (const float*)d_in[9];
    const float* grn_g = (const float*)d_in[10];
    const float* grn_b = (const float*)d_in[11];
    const float* pw2_w = (const float*)d_in[12];
    const float* pw2_b = (const float*)d_in[13];
    float* out = (float*)d_out;

    char* ws = (char*)d_ws;
    float*          freqs = (float*)(ws + OFF_FREQS);
    unsigned short* x     = (unsigned short*)(ws + OFF_X);
    unsigned short* xln   = (unsigned short*)(ws + OFF_XLN);
    unsigned short* h     = (unsigned short*)(ws + OFF_H);
    unsigned short* w1t   = (unsigned short*)(ws + OFF_W1T);
    unsigned short* w2t   = (unsigned short*)(ws + OFF_W2T);
    unsigned short* w2s   = (unsigned short*)(ws + OFF_W2S);
    float*          gxp   = (float*)(ws + OFF_GXP);
    float*          nx    = (float*)(ws + OFF_NX);
    float*          bias2 = (float*)(ws + OFF_B2);
    int*            pos   = (int*)(ws + OFF_POS);
    int*            lens  = (int*)(ws + OFF_LENS);

    freqs_kernel<<<LL, 256, 0, stream>>>(freqs);
    wtrans_kernel<<<dim3(HH / 64, DD / 64, NL), 256, 0, stream>>>(pw1_w, w1t, DD, HH);
    wtrans_kernel<<<dim3(DD / 64, HH / 64, NL), 256, 0, stream>>>(pw2_w, w2t, HH, DD);
    bias2_kernel<<<dim3(DD / 8, NL), 512, 0, stream>>>(pw2_b, grn_b, w2t, bias2);
    embed_kernel<<<MM, 64, 0, stream>>>(text, table, freqs, x);

    for (int layer = 0; layer < NL; layer++) {
        conv_ln_kernel<<<MM / (4 * CCH), 256, 0, stream>>>(x,
            dw_w + (size_t)layer * DD * 7, dw_b + (size_t)layer * DD,
            ln_g + (size_t)layer * DD, ln_b + (size_t)layer * DD, xln);

        gemm_bf16_kernel<DD, HH, 0><<<dim3(HH / 256, MM / 256), 512, 0, stream>>>(
            xln, w1t + (size_t)layer * HH * DD, pw1_b + (size_t)layer * HH,
            h, nullptr, nullptr, gxp);

        grn_stats_kernel<<<BB, 1024, 0, stream>>>(gxp, grn_g + (size_t)layer * HH, nx);

        w2scale_kernel<<<dim3(DD * HH / (256 * 8), BB), 256, 0, stream>>>(
            w2t + (size_t)layer * DD * HH, nx, w2s);

        gemm_bf16_kernel<HH, DD, 1><<<dim3(DD / 256, MM / 256), 512, 0, stream>>>(
            h, w2s, bias2 + (size_t)layer * DD,
            nullptr, x, text, gxp);
    }

    upscan_kernel<<<BB, 256, 0, stream>>>(text, audio, pos, lens);
    upgather_kernel<<<MM, 128, 0, stream>>>(x, pos, lens, out);
}

// Round 21
// 526.674 us; speedup vs baseline: 1.2439x; 1.0048x over previous
//
#include <hip/hip_runtime.h>
#include <hip/hip_bf16.h>

#define BB 16
#define LL 2048
#define DD 512
#define HH 1024
#define NL 4
#define MM (BB*LL)   // 32768

typedef __attribute__((ext_vector_type(8))) short bh8;
typedef __attribute__((ext_vector_type(4))) float f4;
typedef __attribute__((ext_vector_type(4))) unsigned short us4;

typedef __attribute__((address_space(3))) unsigned int lds_u32;
typedef __attribute__((address_space(1))) const unsigned int glob_u32;

__device__ __forceinline__ void gld_lds16(const void* g, void* l) {
    __builtin_amdgcn_global_load_lds((glob_u32*)g, (lds_u32*)l, 16, 0, 0);
}

__device__ __forceinline__ unsigned short f2bf(float f) {
    unsigned int u = __float_as_uint(f);
    unsigned int r = (u + 0x7FFFu + ((u >> 16) & 1u)) >> 16;
    return (unsigned short)r;
}
__device__ __forceinline__ float bf2f(unsigned short u) {
    return __uint_as_float(((unsigned int)u) << 16);
}

// fast GELU (tanh form, abs err ~1e-4)
__device__ __forceinline__ float gelu_f(float v) {
    float y = 0.7978845608028654f * v * fmaf(0.044715f, v * v, 1.0f);
    float e = __expf(2.0f * y);
    float th = 1.0f - 2.0f * __builtin_amdgcn_rcpf(e + 1.0f);
    return 0.5f * v * (1.0f + th);
}

// ---------------- FREQS_CIS table [L, D]
__global__ __launch_bounds__(256) void freqs_kernel(float* __restrict__ fr) {
    int idx = blockIdx.x * 256 + threadIdx.x;
    int l = idx >> 8;
    int j = idx & 255;
    float f = exp2f(-(float)j * 0.051905126482615036f);  // log2(10000)/256
    float a = (float)l * f;
    fr[(size_t)l * DD + j]       = cosf(a);
    fr[(size_t)l * DD + 256 + j] = sinf(a);
}

// ---------------- weight transpose+convert: [NL][R][C] f32 -> [NL][C][R] bf16
__global__ __launch_bounds__(256) void wtrans_kernel(const float* __restrict__ w,
                                                     unsigned short* __restrict__ wt,
                                                     int R, int C) {
    __shared__ float ls[64][65];
    int layer = blockIdx.z;
    int tr = blockIdx.y;
    int tc = blockIdx.x;
    const float* src = w + (size_t)layer * R * C + (size_t)(tr * 64) * C + tc * 64;
    int t = threadIdx.x;
    #pragma unroll
    for (int s = 0; s < 4; s++) {
        int r = (t >> 4) + 16 * s, c = (t & 15) * 4;
        f4 v = *(const f4*)(src + (size_t)r * C + c);
        ls[r][c] = v.x; ls[r][c + 1] = v.y; ls[r][c + 2] = v.z; ls[r][c + 3] = v.w;
    }
    __syncthreads();
    unsigned short* dst = wt + (size_t)layer * R * C + (size_t)(tc * 64) * R + tr * 64;
    #pragma unroll
    for (int s = 0; s < 2; s++) {
        int idx = t + 256 * s;
        int c = idx >> 3;
        int r8 = (idx & 7) * 8;
        bh8 o;
        #pragma unroll
        for (int e = 0; e < 8; e++) o[e] = (short)f2bf(ls[r8 + e][c]);
        *(bh8*)(dst + (size_t)c * R + r8) = o;
    }
}

// ---------------- bias2[n] = pw2_b[n] + sum_k grn_b[k] * W2[k][n]
// Parallelized: grid (DD/8, NL), 512 threads; each wave owns one n, 64 lanes x 16 k.
__global__ __launch_bounds__(512) void bias2_kernel(const float* __restrict__ pw2_b,
                                                    const float* __restrict__ grn_b,
                                                    const unsigned short* __restrict__ w2t,
                                                    float* __restrict__ bias2) {
    int layer = blockIdx.y;
    int n = blockIdx.x * 8 + (threadIdx.x >> 6);
    int lane = threadIdx.x & 63;
    const unsigned short* wp = w2t + (size_t)layer * DD * HH + (size_t)n * HH + lane * 16;
    const float* gbp = grn_b + (size_t)layer * HH + lane * 16;
    float s = 0.f;
    #pragma unroll
    for (int q = 0; q < 2; q++) {
        bh8 wv = *(const bh8*)(wp + q * 8);
        #pragma unroll
        for (int e = 0; e < 8; e++) s = fmaf(gbp[q * 8 + e], bf2f((unsigned short)wv[e]), s);
    }
    #pragma unroll
    for (int off = 1; off <= 32; off <<= 1) s += __shfl_xor(s, off, 64);
    if (lane == 0) bias2[(size_t)layer * DD + n] = pw2_b[(size_t)layer * DD + n] + s;
}

// ---------------- embedding + freqs + mask -> bf16 x (256 threads = 4 rows/block)
__global__ __launch_bounds__(256) void embed_kernel(const int* __restrict__ text,
                                                    const float* __restrict__ table,
                                                    const float* __restrict__ fr,
                                                    unsigned short* __restrict__ x) {
    int bid = blockIdx.x * 4 + (threadIdx.x >> 6);   // b*L + l
    int t = threadIdx.x & 63;                        // 64 lanes, 8 ch each
    int l = bid & (LL - 1);
    int d0 = t * 8;
    int tok = text[bid] + 1;
    bh8 o;
    if (tok != 0) {
        const float* e = table + (size_t)tok * DD + d0;
        const float* f = fr + (size_t)l * DD + d0;
        #pragma unroll
        for (int k = 0; k < 8; k++) o[k] = (short)f2bf(e[k] + f[k]);
    } else {
        #pragma unroll
        for (int k = 0; k < 8; k++) o[k] = 0;
    }
    *(bh8*)(x + (size_t)bid * DD + d0) = o;
}

// ---------------- depthwise conv7 + bias + LayerNorm -> bf16 (x input is bf16)
#define CCH 16
__global__ __launch_bounds__(256) void conv_ln_kernel(const unsigned short* __restrict__ x,
                                                      const float* __restrict__ dw_w,
                                                      const float* __restrict__ dw_b,
                                                      const float* __restrict__ ln_g,
                                                      const float* __restrict__ ln_b,
                                                      unsigned short* __restrict__ xln) {
    const int t = threadIdx.x;
    const int lane = t & 63, wv = t >> 6;
    const int chunk = blockIdx.x * 4 + wv;
    const int row0 = chunk * CCH;
    const int l0 = row0 & (LL - 1);
    const int d0 = lane * 8;
    const unsigned short* xb = x + ((size_t)(row0 >> 11) * LL) * DD + d0;

    float w[7][8], cb[8], g[8], be[8];
    #pragma unroll
    for (int e = 0; e < 8; e++) {
        #pragma unroll
        for (int k = 0; k < 7; k++) w[k][e] = dw_w[(d0 + e) * 7 + k];
        cb[e] = dw_b[d0 + e];
        g[e]  = ln_g[d0 + e];
        be[e] = ln_b[d0 + e];
    }

    float ring[8][8];
    #pragma unroll
    for (int ii = 0; ii < 8; ii++) {
        int i = ii - 3;
        int s = i & 7;
        int l = l0 + i;
        bool ok = (unsigned)l < LL;
        if (ok) {
            bh8 v = *(const bh8*)(xb + (size_t)l * DD);
            #pragma unroll
            for (int e = 0; e < 8; e++) ring[s][e] = bf2f((unsigned short)v[e]);
        } else {
            #pragma unroll
            for (int e = 0; e < 8; e++) ring[s][e] = 0.f;
        }
    }

    #pragma unroll
    for (int r = 0; r < CCH; r++) {
        float acc[8];
        #pragma unroll
        for (int e = 0; e < 8; e++) acc[e] = cb[e];
        #pragma unroll
        for (int k = 0; k < 7; k++) {
            int s = (r + k - 3) & 7;
            #pragma unroll
            for (int e = 0; e < 8; e++) acc[e] = fmaf(w[k][e], ring[s][e], acc[e]);
        }
        if (r + 5 <= CCH + 2) {
            int s = (r + 5) & 7;
            int l = l0 + r + 5;
            bool ok = (unsigned)l < LL;
            if (ok) {
                bh8 v = *(const bh8*)(xb + (size_t)l * DD);
                #pragma unroll
                for (int e = 0; e < 8; e++) ring[s][e] = bf2f((unsigned short)v[e]);
            } else {
                #pragma unroll
                for (int e = 0; e < 8; e++) ring[s][e] = 0.f;
            }
        }
        float s1 = 0.f, s2 = 0.f;
        #pragma unroll
        for (int e = 0; e < 8; e++) { s1 += acc[e]; s2 = fmaf(acc[e], acc[e], s2); }
        #pragma unroll
        for (int off = 1; off <= 32; off <<= 1) {
            s1 += __shfl_xor(s1, off, 64);
            s2 += __shfl_xor(s2, off, 64);
        }
        float mu = s1 * (1.0f / DD);
        float var = s2 * (1.0f / DD) - mu * mu;
        float rstd = rsqrtf(var + 1e-6f);
        bh8 o;
        #pragma unroll
        for (int e = 0; e < 8; e++) o[e] = (short)f2bf((acc[e] - mu) * rstd * g[e] + be[e]);
        *(bh8*)(xln + (size_t)(row0 + r) * DD + d0) = o;
    }
}

// ---------------- bf16 MFMA GEMM: 256x256 tile, 8 waves (2Mx4N), BK=64.
// Provably-correct 2-phase double-buffer (R9). XOR-swizzled LDS, XCD swizzle, setprio.
// MODE 0 (GEMM1): h = bf16(gelu(C+bias)); writes 64-row-block partials of sum(h^2) to aux
// MODE 1 (GEMM2): B is per-batch pre-scaled W2 (batch = m0>>11);
//   epilogue: stage C+bias as f32 in LDS (2 half-passes of 128 rows), then all 512
//   threads do coalesced us4 RMW on bf16 x: x = mask ? 0 : bf16(C + bias + f32(x)).
template<int KDIM, int NDIM, int MODE>
__global__ __launch_bounds__(512) void gemm_bf16_kernel(const unsigned short* __restrict__ A,
                                                        const unsigned short* __restrict__ Bt,
                                                        const float* __restrict__ bias,
                                                        unsigned short* __restrict__ hout,
                                                        unsigned short* __restrict__ xio,
                                                        const int* __restrict__ text,
                                                        float* __restrict__ aux) {
    __shared__ unsigned short lsbuf[65536];    // 128KB: A dbuf (0..32767), B dbuf (32768..65535)
    const int tid = threadIdx.x;
    constexpr int NX = NDIM / 256;
    constexpr int NWG = NX * (MM / 256);
    constexpr int NT = KDIM / 64;
    const int id = blockIdx.y * NX + blockIdx.x;
    const int sw = (id & 7) * (NWG / 8) + (id >> 3);     // XCD-chunked (NWG%8==0)
    const int m0 = (sw / NX) * 256;
    const int n0 = (sw % NX) * 256;

    const int lane = tid & 63, wid = tid >> 6;
    const int wm = wid >> 2, wn = wid & 3;               // wave tile: 128 rows x 64 cols
    const int ln = lane & 15;
    const int kq0 = ((lane >> 4) * 8) ^ ((lane & 7) << 3);
    const int kq1 = (32 + (lane >> 4) * 8) ^ ((lane & 7) << 3);
    const int arow = (wm * 128 + ln) * 64;               // + i*1024
    const int brow = (wn * 64 + ln) * 64;                // + j*1024

    const int srow = tid >> 3;
    const int scol = ((tid & 7) ^ (srow & 7)) << 3;      // inverse-swizzled global col (shorts)
    const int sdst = tid * 8;                            // LDS dest (shorts), +4096 for q=1
    const unsigned short* Asrc = A + ((size_t)m0 + srow) * KDIM + scol;
    const unsigned short* Bsrc;
    if constexpr (MODE == 0) Bsrc = Bt + ((size_t)n0 + srow) * KDIM + scol;
    else                     Bsrc = Bt + ((size_t)(m0 >> 11) * NDIM + n0 + srow) * KDIM + scol;

    f4 acc[8][4];
    #pragma unroll
    for (int i = 0; i < 8; i++)
        #pragma unroll
        for (int j = 0; j < 4; j++) acc[i][j] = (f4){0.f, 0.f, 0.f, 0.f};

#define LSA(bb) (lsbuf + (bb) * 16384)
#define LSB(bb) (lsbuf + 32768 + (bb) * 16384)
#define STG_ALL(bb, ko) do { _Pragma("unroll") for (int h = 0; h < 2; h++) {               \
    gld_lds16(Asrc + (size_t)(h * 128) * KDIM + (ko), LSA(bb) + h * 8192 + sdst);          \
    gld_lds16(Asrc + (size_t)(h * 128 + 64) * KDIM + (ko), LSA(bb) + h * 8192 + 4096 + sdst); \
    gld_lds16(Bsrc + (size_t)(h * 128) * KDIM + (ko), LSB(bb) + h * 8192 + sdst);          \
    gld_lds16(Bsrc + (size_t)(h * 128 + 64) * KDIM + (ko), LSB(bb) + h * 8192 + 4096 + sdst); } } while (0)
#define BOUNDARY do { asm volatile("s_waitcnt vmcnt(0)" ::: "memory");                     \
    __builtin_amdgcn_s_barrier(); __builtin_amdgcn_sched_barrier(0); } while (0)
#define RD_A03 do { _Pragma("unroll") for (int i = 0; i < 4; i++) {                        \
    aF[i][0] = *(bh8*)(LSA(cur) + arow + i * 1024 + kq0);                                  \
    aF[i][1] = *(bh8*)(LSA(cur) + arow + i * 1024 + kq1); } } while (0)
#define RD_A47 do { _Pragma("unroll") for (int i = 0; i < 4; i++) {                        \
    aF[i][0] = *(bh8*)(LSA(cur) + arow + (i + 4) * 1024 + kq0);                            \
    aF[i][1] = *(bh8*)(LSA(cur) + arow + (i + 4) * 1024 + kq1); } } while (0)
#define RD_B01 do { _Pragma("unroll") for (int j = 0; j < 2; j++) {                        \
    b0F[j][0] = *(bh8*)(LSB(cur) + brow + j * 1024 + kq0);                                 \
    b0F[j][1] = *(bh8*)(LSB(cur) + brow + j * 1024 + kq1); } } while (0)
#define RD_B23 do { _Pragma("unroll") for (int j = 0; j < 2; j++) {                        \
    b1F[j][0] = *(bh8*)(LSB(cur) + brow + (j + 2) * 1024 + kq0);                           \
    b1F[j][1] = *(bh8*)(LSB(cur) + brow + (j + 2) * 1024 + kq1); } } while (0)
#define MFMA_Q(i0, j0, bf) do { __builtin_amdgcn_s_setprio(1);                             \
    _Pragma("unroll") for (int i = 0; i < 4; i++)                                          \
    _Pragma("unroll") for (int j = 0; j < 2; j++) {                                        \
        acc[i + i0][j + j0] = __builtin_amdgcn_mfma_f32_16x16x32_bf16(aF[i][0], bf[j][0], acc[i + i0][j + j0], 0, 0, 0); \
        acc[i + i0][j + j0] = __builtin_amdgcn_mfma_f32_16x16x32_bf16(aF[i][1], bf[j][1], acc[i + i0][j + j0], 0, 0, 0); } \
    __builtin_amdgcn_s_setprio(0); } while (0)

    STG_ALL(0, 0);
    BOUNDARY;

    bh8 aF[4][2], b0F[2][2], b1F[2][2];
    for (int kt = 0; kt < NT; kt++) {
        const int cur = kt & 1, nb = cur ^ 1;
        const bool more = (kt + 1 < NT);
        if (more) { STG_ALL(nb, (kt + 1) * 64); }
        __builtin_amdgcn_sched_barrier(0);       // keep stage issues at top
        RD_A03; RD_B01;
        MFMA_Q(0, 0, b0F);
        RD_B23;
        MFMA_Q(0, 2, b1F);
        RD_A47;
        MFMA_Q(4, 2, b1F);
        MFMA_Q(4, 0, b0F);
        if (more) { BOUNDARY; }
    }
#undef STG_ALL
#undef BOUNDARY
#undef RD_A03
#undef RD_A47
#undef RD_B01
#undef RD_B23
#undef MFMA_Q
#undef LSA
#undef LSB

    const int rowOff = (lane >> 4) * 4;
    const int colOff = ln;
    if constexpr (MODE == 0) {
        float sj0[4] = {0.f, 0.f, 0.f, 0.f};
        float sj1[4] = {0.f, 0.f, 0.f, 0.f};
        #pragma unroll
        for (int i = 0; i < 8; i++) {
            #pragma unroll
            for (int j = 0; j < 4; j++) {
                int n = n0 + wn * 64 + j * 16 + colOff;
                float bn = bias[n];
                #pragma unroll
                for (int r = 0; r < 4; r++) {
                    int m = m0 + wm * 128 + i * 16 + rowOff + r;
                    float v = gelu_f(acc[i][j][r] + bn);
                    hout[(size_t)m * NDIM + n] = f2bf(v);
                    if (i < 4) sj0[j] = fmaf(v, v, sj0[j]);
                    else       sj1[j] = fmaf(v, v, sj1[j]);
                }
            }
        }
        #pragma unroll
        for (int j = 0; j < 4; j++) {
            sj0[j] += __shfl_xor(sj0[j], 16, 64);
            sj0[j] += __shfl_xor(sj0[j], 32, 64);
            sj1[j] += __shfl_xor(sj1[j], 16, 64);
            sj1[j] += __shfl_xor(sj1[j], 32, 64);
        }
        if (lane < 16) {
            int rb = (m0 + wm * 128) >> 6;       // 64-row blocks
            #pragma unroll
            for (int j = 0; j < 4; j++) {
                aux[(size_t)rb * HH + n0 + wn * 64 + j * 16 + lane] = sj0[j];
                aux[(size_t)(rb + 1) * HH + n0 + wn * 64 + j * 16 + lane] = sj1[j];
            }
        }
    } else {
        // staged coalesced RMW epilogue
        __syncthreads();                          // all waves done reading last K-tile
        float* cf = (float*)lsbuf;                // 128 x 256 f32 = 128KB
        #pragma unroll
        for (int half = 0; half < 2; half++) {
            if (wm == half) {
                #pragma unroll
                for (int i = 0; i < 8; i++)
                    #pragma unroll
                    for (int j = 0; j < 4; j++) {
                        int lc = wn * 64 + j * 16 + colOff;
                        float bn = bias[n0 + lc];
                        #pragma unroll
                        for (int r = 0; r < 4; r++) {
                            int lr = i * 16 + rowOff + r;
                            cf[lr * 256 + lc] = acc[i][j][r] + bn;
                        }
                    }
            }
            __syncthreads();
            #pragma unroll
            for (int k = 0; k < 16; k++) {
                int ci = tid + 512 * k;           // 8192 chunks of 4 cols
                int row = ci >> 6, ch = ci & 63;
                int m = m0 + half * 128 + row;
                size_t gb = (size_t)m * NDIM + n0 + ch * 4;
                bool msk = (text[m] == -1);
                us4 xo = *(const us4*)(xio + gb);
                f4 c = *(const f4*)&cf[row * 256 + ch * 4];
                us4 onew;
                onew.x = msk ? 0 : f2bf(c.x + bf2f(xo.x));
                onew.y = msk ? 0 : f2bf(c.y + bf2f(xo.y));
                onew.z = msk ? 0 : f2bf(c.z + bf2f(xo.z));
                onew.w = msk ? 0 : f2bf(c.w + bf2f(xo.w));
                *(us4*)(xio + gb) = onew;
            }
            __syncthreads();
        }
    }
}

// ---------------- GRN stats: scale[b][ch] = 1 + gg[ch] * Nx[b][ch]
// Widened: 16 blocks x 1024 threads (one thread per channel; 16 waves/block).
__global__ __launch_bounds__(1024) void grn_stats_kernel(const float* __restrict__ gxp,
                                                         const float* __restrict__ gg,
                                                         float* __restrict__ scale) {
    int b = blockIdx.x, ch = threadIdx.x;
    int lane = ch & 63, wv = ch >> 6;
    float acc = 0.f;
    #pragma unroll
    for (int rb = 0; rb < 32; rb++) acc += gxp[(size_t)(b * 32 + rb) * HH + ch];
    float g = sqrtf(acc);
    float s = g;
    #pragma unroll
    for (int off = 1; off <= 32; off <<= 1) s += __shfl_xor(s, off, 64);
    __shared__ float rs[16];
    if (lane == 0) rs[wv] = s;
    __syncthreads();
    float tot = 0.f;
    #pragma unroll
    for (int w = 0; w < 16; w++) tot += rs[w];
    float mean = tot * (1.0f / HH);
    float inv = 1.0f / (mean + 1e-6f);
    scale[(size_t)b * HH + ch] = fmaf(gg[ch], g * inv, 1.0f);
}

// ---------------- per-batch scaled W2: w2s[b][n][k] = bf16(scale[b][k] * w2t[n][k])
__global__ __launch_bounds__(256) void w2scale_kernel(const unsigned short* __restrict__ w2t,
                                                      const float* __restrict__ scale,
                                                      unsigned short* __restrict__ w2s) {
    int b = blockIdx.y;
    size_t idx = ((size_t)blockIdx.x * 256 + threadIdx.x) * 8;   // over DD*HH
    int k = (int)(idx & (HH - 1));
    bh8 w = *(const bh8*)(w2t + idx);
    f4 s0 = *(const f4*)(scale + (size_t)b * HH + k);
    f4 s1 = *(const f4*)(scale + (size_t)b * HH + k + 4);
    float sv[8] = {s0.x,s0.y,s0.z,s0.w,s1.x,s1.y,s1.z,s1.w};
    bh8 o;
    #pragma unroll
    for (int e = 0; e < 8; e++) o[e] = (short)f2bf(bf2f((unsigned short)w[e]) * sv[e]);
    *(bh8*)(w2s + (size_t)b * DD * HH + idx) = o;
}

// ---------------- upsample scan (widened: 1024 threads, 2 chunks, wave-ballot scan)
__global__ __launch_bounds__(1024) void upscan_kernel(const int* __restrict__ text,
                                                      const int* __restrict__ audio,
                                                      int* __restrict__ pos,
                                                      int* __restrict__ lens) {
    int b = blockIdx.x, t = threadIdx.x;
    int lane = t & 63, wv = t >> 6;          // 16 waves
    __shared__ int wt[16], wa[16];
    int voff = 0, aoff = 0;
    for (int c = 0; c < LL / 1024; c++) {
        int l = c * 1024 + t;
        int am = audio[(size_t)b * LL + l];
        int tv = text[(size_t)b * LL + l];
        int valid = (am != 0 && tv != -1) ? 1 : 0;
        unsigned long long mv = __ballot(valid);
        unsigned long long ma = __ballot(am != 0);
        if (lane == 0) { wt[wv] = __popcll(mv); wa[wv] = __popcll(ma); }
        __syncthreads();
        int pre = 0;
        #pragma unroll
        for (int w = 0; w < 16; w++) if (w < wv) pre += wt[w];
        int incl = pre + (int)__popcll(mv << (63 - lane));   // bits 0..lane
        if (valid) pos[(size_t)b * LL + voff + incl - 1] = l;
        int bt = 0, ba = 0;
        #pragma unroll
        for (int w = 0; w < 16; w++) { bt += wt[w]; ba += wa[w]; }
        __syncthreads();
        voff += bt;
        aoff += ba;
    }
    if (t == 0) { lens[b * 2] = aoff; lens[b * 2 + 1] = voff; }
    for (int i = voff + t; i < LL; i += 1024) pos[(size_t)b * LL + i] = LL - 1;
}

// ---------------- upsample gather (x bf16 -> out f32; 128 threads x 4 elems)
__global__ __launch_bounds__(128) void upgather_kernel(const unsigned short* __restrict__ x,
                                                       const int* __restrict__ pos,
                                                       const int* __restrict__ lens,
                                                       float* __restrict__ out) {
    int bid = blockIdx.x;
    int b = bid >> 11;
    int p = bid & (LL - 1);
    int t = threadIdx.x;
    int alen = lens[b * 2], vlen = lens[b * 2 + 1];
    f4 v = {0.f, 0.f, 0.f, 0.f};
    if (p < alen && vlen > 0) {
        int vl = vlen < 1 ? 1 : vlen;
        int base = alen / vl, rem = alen % vl;
        int cut = (vl - rem) * base;
        int j;
        if (p < cut) j = p / (base < 1 ? 1 : base);
        else j = (vl - rem) + (p - cut) / (base + 1);
        j = j < 0 ? 0 : (j > LL - 1 ? LL - 1 : j);
        int s = pos[(size_t)b * LL + j];
        s = s < 0 ? 0 : (s > LL - 1 ? LL - 1 : s);
        us4 u = *(const us4*)(x + ((size_t)b * LL + s) * DD + t * 4);
        v.x = bf2f(u.x); v.y = bf2f(u.y); v.z = bf2f(u.z); v.w = bf2f(u.w);
    }
    *(f4*)(out + (size_t)bid * DD + t * 4) = v;
}

// ---------------- workspace layout (bytes)
#define OFF_FREQS  ((size_t)0)
#define OFF_X      (OFF_FREQS + (size_t)LL * DD * 4)          // 4 MB (freqs f32)
#define OFF_XLN    (OFF_X + (size_t)MM * DD * 2)              // +32 MB (x bf16)
#define OFF_H      (OFF_XLN + (size_t)MM * DD * 2)            // +32 MB
#define OFF_W1T    (OFF_H + (size_t)MM * HH * 2)              // +64 MB
#define OFF_W2T    (OFF_W1T + (size_t)NL * HH * DD * 2)       // +4 MB
#define OFF_GXP    (OFF_W2T + (size_t)NL * DD * HH * 2)       // +4 MB
#define OFF_NX     (OFF_GXP + (size_t)512 * HH * 4)           // +2 MB
#define OFF_B2     (OFF_NX + (size_t)BB * HH * 4)             // +64 KB
#define OFF_POS    (OFF_B2 + (size_t)NL * DD * 4)             // +8 KB
#define OFF_LENS   (OFF_POS + (size_t)BB * LL * 4)            // +128 KB
// w2s (16 MB) overlays xln's region (xln dead between GEMM1(layer) and conv_ln(layer+1))
#define OFF_W2S    OFF_XLN

extern "C" void kernel_launch(void* const* d_in, const int* in_sizes, int n_in,
                              void* d_out, int out_size, void* d_ws, size_t ws_size,
                              hipStream_t stream) {
    const int*   text  = (const int*)d_in[0];
    const int*   audio = (const int*)d_in[1];
    const float* table = (const float*)d_in[3];
    const float* dw_w  = (const float*)d_in[4];
    const float* dw_b  = (const float*)d_in[5];
    const float* ln_g  = (const float*)d_in[6];
    const float* ln_b  = (const float*)d_in[7];
    const float* pw1_w = (const float*)d_in[8];
    const float* pw1_b = (const float*)d_in[9];
    const float* grn_g = (const float*)d_in[10];
    const float* grn_b = (const float*)d_in[11];
    const float* pw2_w = (const float*)d_in[12];
    const float* pw2_b = (const float*)d_in[13];
    float* out = (float*)d_out;

    char* ws = (char*)d_ws;
    float*          freqs = (float*)(ws + OFF_FREQS);
    unsigned short* x     = (unsigned short*)(ws + OFF_X);
    unsigned short* xln   = (unsigned short*)(ws + OFF_XLN);
    unsigned short* h     = (unsigned short*)(ws + OFF_H);
    unsigned short* w1t   = (unsigned short*)(ws + OFF_W1T);
    unsigned short* w2t   = (unsigned short*)(ws + OFF_W2T);
    unsigned short* w2s   = (unsigned short*)(ws + OFF_W2S);
    float*          gxp   = (float*)(ws + OFF_GXP);
    float*          nx    = (float*)(ws + OFF_NX);
    float*          bias2 = (float*)(ws + OFF_B2);
    int*            pos   = (int*)(ws + OFF_POS);
    int*            lens  = (int*)(ws + OFF_LENS);

    freqs_kernel<<<LL, 256, 0, stream>>>(freqs);
    wtrans_kernel<<<dim3(HH / 64, DD / 64, NL), 256, 0, stream>>>(pw1_w, w1t, DD, HH);
    wtrans_kernel<<<dim3(DD / 64, HH / 64, NL), 256, 0, stream>>>(pw2_w, w2t, HH, DD);
    bias2_kernel<<<dim3(DD / 8, NL), 512, 0, stream>>>(pw2_b, grn_b, w2t, bias2);
    embed_kernel<<<MM / 4, 256, 0, stream>>>(text, table, freqs, x);

    for (int layer = 0; layer < NL; layer++) {
        conv_ln_kernel<<<MM / (4 * CCH), 256, 0, stream>>>(x,
            dw_w + (size_t)layer * DD * 7, dw_b + (size_t)layer * DD,
            ln_g + (size_t)layer * DD, ln_b + (size_t)layer * DD, xln);

        gemm_bf16_kernel<DD, HH, 0><<<dim3(HH / 256, MM / 256), 512, 0, stream>>>(
            xln, w1t + (size_t)layer * HH * DD, pw1_b + (size_t)layer * HH,
            h, nullptr, nullptr, gxp);

        grn_stats_kernel<<<BB, 1024, 0, stream>>>(gxp, grn_g + (size_t)layer * HH, nx);

        w2scale_kernel<<<dim3(DD * HH / (256 * 8), BB), 256, 0, stream>>>(
            w2t + (size_t)layer * DD * HH, nx, w2s);

        gemm_bf16_kernel<HH, DD, 1><<<dim3(DD / 256, MM / 256), 512, 0, stream>>>(
            h, w2s, bias2 + (size_t)layer * DD,
            nullptr, x, text, gxp);
    }

    upscan_kernel<<<BB, 1024, 0, stream>>>(text, audio, pos, lens);
    upgather_kernel<<<MM, 128, 0, stream>>>(x, pos, lens, out);
}